// Round 1
// baseline (586.352 us; speedup 1.0000x reference)
//
#include <hip/hip_runtime.h>
#include <math.h>

#define N 3072
#define H 64
#define CAUS 16
#define CSD 32
#define GAT_ALPHA 0.35f

// ---------------------------------------------------------------------------
// out[g][f] += sum_{c in K-slice} X[c][g] * W[c][f]   (X: N x N row-major, W: N x 64)
// grid: (96 gene-tiles, 4 K-slices), 256 threads. Requires out zeroed first.
__global__ __launch_bounds__(256) void k_xt_gemm(const float* __restrict__ X,
                                                 const float* __restrict__ W,
                                                 float* __restrict__ out) {
  __shared__ float xs[32 * 32];
  __shared__ float wsh[32 * 64];
  int t = threadIdx.x;
  int g0 = blockIdx.x * 32;
  int c0 = blockIdx.y * (N / 4);
  int g = t & 31, fh = t >> 5;  // g: 0..31, fh: 0..7 (f = fh*8..fh*8+7)
  float acc[8] = {0, 0, 0, 0, 0, 0, 0, 0};
  for (int kc = 0; kc < N / 4; kc += 32) {
    int cbase = c0 + kc;
#pragma unroll
    for (int k = 0; k < 4; k++) {
      int lin = t + k * 256;
      xs[lin] = X[(cbase + (lin >> 5)) * N + g0 + (lin & 31)];
    }
    const float4* W4 = (const float4*)(W + cbase * H);
    float4* ws4 = (float4*)wsh;
#pragma unroll
    for (int k = 0; k < 2; k++) {
      int lin = t + k * 256;
      ws4[lin] = W4[lin];
    }
    __syncthreads();
#pragma unroll 8
    for (int kk = 0; kk < 32; kk++) {
      float xv = xs[kk * 32 + g];
      const float4* wr = (const float4*)(wsh + kk * 64 + fh * 8);
      float4 w0 = wr[0], w1 = wr[1];
      acc[0] += xv * w0.x; acc[1] += xv * w0.y; acc[2] += xv * w0.z; acc[3] += xv * w0.w;
      acc[4] += xv * w1.x; acc[5] += xv * w1.y; acc[6] += xv * w1.z; acc[7] += xv * w1.w;
    }
    __syncthreads();
  }
  float* orow = out + (g0 + g) * H + fh * 8;
#pragma unroll
  for (int i = 0; i < 8; i++) atomicAdd(orow + i, acc[i]);
}

// ---------------------------------------------------------------------------
// s_dst[r] = h[r,:].a[0:64]; s_src[r] = h[r,:].a[64:128]. One wave per row.
__global__ __launch_bounds__(256) void k_sd(const float* __restrict__ h,
                                            const float* __restrict__ a,
                                            float* __restrict__ sdst,
                                            float* __restrict__ ssrc) {
  int row = blockIdx.x * 4 + (threadIdx.x >> 6);
  int lane = threadIdx.x & 63;
  float v = h[row * H + lane];
  float d1 = v * a[lane];
  float d2 = v * a[H + lane];
  for (int off = 32; off > 0; off >>= 1) {
    d1 += __shfl_xor(d1, off);
    d2 += __shfl_xor(d2, off);
  }
  if (lane == 0) { sdst[row] = d1; ssrc[row] = d2; }
}

// ---------------------------------------------------------------------------
// Online softmax stats per row: m[i] = max_j masked e_ij, Z[i] = sum exp(e-m).
__global__ __launch_bounds__(256) void k_stats(const int* __restrict__ adj,
                                               const float* __restrict__ sdst,
                                               const float* __restrict__ ssrc,
                                               float* __restrict__ mrow,
                                               float* __restrict__ zrow) {
  int row = blockIdx.x * 4 + (threadIdx.x >> 6);
  int lane = threadIdx.x & 63;
  float si = ssrc[row];
  const int* ar = adj + row * N;
  float M = -INFINITY, S = 0.f;
  for (int j = lane; j < N; j += 64) {
    if (ar[j] > 0) {
      float e = si + sdst[j];
      e = e > 0.f ? e : GAT_ALPHA * e;
      if (e > M) { S = S * __expf(M - e) + 1.0f; M = e; }
      else        S += __expf(e - M);
    }
  }
  for (int off = 32; off > 0; off >>= 1) {
    float M2 = __shfl_xor(M, off), S2 = __shfl_xor(S, off);
    float nM = fmaxf(M, M2);
    float a1 = (S > 0.f) ? S * __expf(M - nM) : 0.f;
    float a2 = (S2 > 0.f) ? S2 * __expf(M2 - nM) : 0.f;
    M = nM; S = a1 + a2;
  }
  if (lane == 0) { mrow[row] = M; zrow[row] = fmaxf(S, 1e-30f); }
}

// ---------------------------------------------------------------------------
// h_gat[i,:] = elu( (1/Z_i) * sum_j masked exp(e_ij - m_i) * h[j,:] )
// 16 rows per block; j staged 64-wide; weights precomputed into LDS once.
__global__ __launch_bounds__(256) void k_gat_av(const float* __restrict__ hptr,
                                                const int* __restrict__ adj,
                                                const float* __restrict__ sdst,
                                                const float* __restrict__ ssrc,
                                                const float* __restrict__ mrow,
                                                const float* __restrict__ zrow,
                                                float* __restrict__ hgat) {
  __shared__ float4 hs4[64 * 16];
  __shared__ float wsm[16][65];
  __shared__ float ssrc_s[16], m_s[16], zinv_s[16];
  int t = threadIdx.x;
  int row0 = blockIdx.x * 16;
  if (t < 16) {
    ssrc_s[t] = ssrc[row0 + t];
    m_s[t] = mrow[row0 + t];
    zinv_s[t] = 1.0f / zrow[row0 + t];
  }
  __syncthreads();
  int r = t >> 4, fq = t & 15;
  float4 acc = make_float4(0.f, 0.f, 0.f, 0.f);
  for (int j0 = 0; j0 < N; j0 += 64) {
    const float4* H4 = (const float4*)hptr + j0 * (H / 4);
#pragma unroll
    for (int k = 0; k < 4; k++) {
      int lin = t + k * 256;
      hs4[lin] = H4[lin];
    }
#pragma unroll
    for (int k = 0; k < 4; k++) {
      int lin = t + k * 256;
      int rr = lin >> 6, jj = lin & 63;
      int av = adj[(row0 + rr) * N + j0 + jj];
      float e = ssrc_s[rr] + sdst[j0 + jj];
      e = e > 0.f ? e : GAT_ALPHA * e;
      wsm[rr][jj] = (av > 0) ? __expf(e - m_s[rr]) : 0.0f;
    }
    __syncthreads();
#pragma unroll 8
    for (int jj = 0; jj < 64; jj++) {
      float wv = wsm[r][jj];
      float4 hv = hs4[jj * 16 + fq];
      acc.x += wv * hv.x; acc.y += wv * hv.y; acc.z += wv * hv.z; acc.w += wv * hv.w;
    }
    __syncthreads();
  }
  float zi = zinv_s[r];
  float4 o;
  o.x = acc.x * zi; o.y = acc.y * zi; o.z = acc.z * zi; o.w = acc.w * zi;
  o.x = o.x > 0.f ? o.x : __expf(o.x) - 1.f;
  o.y = o.y > 0.f ? o.y : __expf(o.y) - 1.f;
  o.z = o.z > 0.f ? o.z : __expf(o.z) - 1.f;
  o.w = o.w > 0.f ? o.w : __expf(o.w) - 1.f;
  ((float4*)hgat)[(row0 + r) * (H / 4) + fq] = o;
}

// ---------------------------------------------------------------------------
// GCN aggregation: out[i,:] = relu( dis[i] * sum_j (adj[i][j] + delta_ij)*dis[j] * tin[j,:] )
__global__ __launch_bounds__(256) void k_gcn_agg(const float* __restrict__ tin,
                                                 const int* __restrict__ adj,
                                                 const float* __restrict__ dis,
                                                 float* __restrict__ out) {
  __shared__ float4 hs4[64 * 16];
  __shared__ float wsm[16][65];
  __shared__ float dis_s[16];
  int t = threadIdx.x;
  int row0 = blockIdx.x * 16;
  if (t < 16) dis_s[t] = dis[row0 + t];
  __syncthreads();
  int r = t >> 4, fq = t & 15;
  float4 acc = make_float4(0.f, 0.f, 0.f, 0.f);
  for (int j0 = 0; j0 < N; j0 += 64) {
    const float4* T4 = (const float4*)tin + j0 * (H / 4);
#pragma unroll
    for (int k = 0; k < 4; k++) {
      int lin = t + k * 256;
      hs4[lin] = T4[lin];
    }
#pragma unroll
    for (int k = 0; k < 4; k++) {
      int lin = t + k * 256;
      int rr = lin >> 6, jj = lin & 63;
      int col = j0 + jj;
      float av = (float)adj[(row0 + rr) * N + col] + ((row0 + rr) == col ? 1.0f : 0.0f);
      wsm[rr][jj] = av * dis[col];
    }
    __syncthreads();
#pragma unroll 8
    for (int jj = 0; jj < 64; jj++) {
      float wv = wsm[r][jj];
      float4 hv = hs4[jj * 16 + fq];
      acc.x += wv * hv.x; acc.y += wv * hv.y; acc.z += wv * hv.z; acc.w += wv * hv.w;
    }
    __syncthreads();
  }
  float dr = dis_s[r];
  float4 o;
  o.x = fmaxf(acc.x * dr, 0.f);
  o.y = fmaxf(acc.y * dr, 0.f);
  o.z = fmaxf(acc.z * dr, 0.f);
  o.w = fmaxf(acc.w * dr, 0.f);
  ((float4*)out)[(row0 + r) * (H / 4) + fq] = o;
}

// ---------------------------------------------------------------------------
// Per-row VAE encode + reparam + diffusion fusion. 16 rows/block.
__global__ __launch_bounds__(256) void k_vae(const float* __restrict__ hgat,
                                             const float* __restrict__ eps,
                                             const float* __restrict__ Wmu,
                                             const float* __restrict__ bmu,
                                             const float* __restrict__ Wlv,
                                             const float* __restrict__ blv,
                                             const float* __restrict__ Wd,
                                             const float* __restrict__ bd,
                                             float* __restrict__ mu_o,
                                             float* __restrict__ lv_o,
                                             float* __restrict__ cs_o) {
  __shared__ float hs[16][65];
  __shared__ float zs[16][17];
  __shared__ float wmu_s[64 * 16];
  __shared__ float wlv_s[64 * 16];
  __shared__ float wd_s[80 * 32];
  int t = threadIdx.x;
  int row0 = blockIdx.x * 16;
#pragma unroll
  for (int k = 0; k < 4; k++) {
    int lin = t + k * 256;
    hs[lin >> 6][lin & 63] = hgat[row0 * H + lin];
    wmu_s[lin] = Wmu[lin];
    wlv_s[lin] = Wlv[lin];
  }
#pragma unroll
  for (int k = 0; k < 10; k++) {
    int lin = t + k * 256;
    wd_s[lin] = Wd[lin];
  }
  __syncthreads();
  int r = t >> 4, kk = t & 15;
  float mu = bmu[kk], lv = blv[kk];
#pragma unroll 8
  for (int l = 0; l < 64; l++) {
    float hv = hs[r][l];
    mu += hv * wmu_s[l * 16 + kk];
    lv += hv * wlv_s[l * 16 + kk];
  }
  float z = mu + eps[(row0 + r) * CAUS + kk] * __expf(0.5f * lv);
  mu_o[(row0 + r) * CAUS + kk] = mu;
  lv_o[(row0 + r) * CAUS + kk] = lv;
  zs[r][kk] = z;
  __syncthreads();
#pragma unroll
  for (int p = 0; p < 2; p++) {
    int lin = t + p * 256;
    int rr = lin >> 5, c = lin & 31;
    float acc = bd[c];
#pragma unroll 4
    for (int q = 0; q < 16; q++) acc += zs[rr][q] * wd_s[q * 32 + c];
#pragma unroll 8
    for (int l = 0; l < 64; l++) acc += hs[rr][l] * wd_s[(16 + l) * 32 + c];
    cs_o[(row0 + rr) * CSD + c] = fmaxf(acc, 0.f);
  }
}

// ---------------------------------------------------------------------------
// x_recon = sigmoid(cs @ W_dec + b_dec). 32 rows x 128 cols per block.
__global__ __launch_bounds__(256) void k_dec(const float* __restrict__ cs,
                                             const float* __restrict__ Wdec,
                                             const float* __restrict__ bdec,
                                             float* __restrict__ xr) {
  __shared__ float cs_s[32][33];
  __shared__ float4 wd4[32 * 32];
  int t = threadIdx.x;
  int c0 = blockIdx.x * 128;
  int row0 = blockIdx.y * 32;
#pragma unroll
  for (int k = 0; k < 4; k++) {
    int lin = t + k * 256;
    cs_s[lin >> 5][lin & 31] = cs[(row0 + (lin >> 5)) * CSD + (lin & 31)];
    int kr = lin >> 5, c4 = lin & 31;
    wd4[lin] = ((const float4*)(Wdec + kr * N + c0))[c4];
  }
  __syncthreads();
  int rq = t >> 5, cq = t & 31;
  float4 acc[4];
#pragma unroll
  for (int ri = 0; ri < 4; ri++) acc[ri] = make_float4(0.f, 0.f, 0.f, 0.f);
#pragma unroll 8
  for (int k = 0; k < 32; k++) {
    float4 wv = wd4[k * 32 + cq];
#pragma unroll
    for (int ri = 0; ri < 4; ri++) {
      float cv = cs_s[rq * 4 + ri][k];
      acc[ri].x += cv * wv.x; acc[ri].y += cv * wv.y;
      acc[ri].z += cv * wv.z; acc[ri].w += cv * wv.w;
    }
  }
  float4 bv = ((const float4*)(bdec + c0))[cq];
#pragma unroll
  for (int ri = 0; ri < 4; ri++) {
    float4 v = acc[ri];
    v.x = 1.f / (1.f + __expf(-(v.x + bv.x)));
    v.y = 1.f / (1.f + __expf(-(v.y + bv.y)));
    v.z = 1.f / (1.f + __expf(-(v.z + bv.z)));
    v.w = 1.f / (1.f + __expf(-(v.w + bv.w)));
    ((float4*)(xr + (row0 + rq * 4 + ri) * N + c0))[cq] = v;
  }
}

// ---------------------------------------------------------------------------
// dis[i] = (rowsum(adj) + 1)^-1/2
__global__ __launch_bounds__(256) void k_deg(const int* __restrict__ adj,
                                             float* __restrict__ dis) {
  int row = blockIdx.x * 4 + (threadIdx.x >> 6);
  int lane = threadIdx.x & 63;
  const int* ar = adj + row * N;
  int s = 0;
  for (int j = lane; j < N; j += 64) s += ar[j];
  for (int off = 32; off > 0; off >>= 1) s += __shfl_xor(s, off);
  if (lane == 0) dis[row] = rsqrtf((float)s + 1.0f);
}

// ---------------------------------------------------------------------------
// t2 = h1 @ W_gcn2 (64x64). 4 rows/block.
__global__ __launch_bounds__(256) void k_h1w2(const float* __restrict__ h1,
                                              const float* __restrict__ W2,
                                              float* __restrict__ t2) {
  __shared__ float w2s[64 * 64];
  __shared__ float hs[4][65];
  int t = threadIdx.x;
  int row0 = blockIdx.x * 4;
#pragma unroll
  for (int k = 0; k < 16; k++) w2s[t + k * 256] = W2[t + k * 256];
  hs[t >> 6][t & 63] = h1[row0 * H + t];
  __syncthreads();
  int r = t >> 6, f = t & 63;
  float acc = 0.f;
#pragma unroll 8
  for (int l = 0; l < 64; l++) acc += hs[r][l] * w2s[l * 64 + f];
  t2[(row0 + r) * H + f] = acc;
}

// ---------------------------------------------------------------------------
// ie = concat(h2, cs)
__global__ __launch_bounds__(256) void k_ie(const float* __restrict__ h2,
                                            const float* __restrict__ cs,
                                            float* __restrict__ ie) {
  int idx = blockIdx.x * 256 + threadIdx.x;
  int i = idx / 96, k = idx - i * 96;
  ie[idx] = (k < 64) ? h2[i * H + k] : cs[i * CSD + (k - 64)];
}

// ---------------------------------------------------------------------------
extern "C" void kernel_launch(void* const* d_in, const int* in_sizes, int n_in,
                              void* d_out, int out_size, void* d_ws, size_t ws_size,
                              hipStream_t stream) {
  const float* x    = (const float*)d_in[0];
  const int*   adj  = (const int*)d_in[1];
  const float* eps  = (const float*)d_in[2];
  const float* Wgat = (const float*)d_in[3];
  const float* agat = (const float*)d_in[4];
  const float* Wmu  = (const float*)d_in[5];
  const float* bmu  = (const float*)d_in[6];
  const float* Wlv  = (const float*)d_in[7];
  const float* blv  = (const float*)d_in[8];
  const float* Wdif = (const float*)d_in[9];
  const float* bdif = (const float*)d_in[10];
  const float* Wdec = (const float*)d_in[11];
  const float* bdec = (const float*)d_in[12];
  const float* Wg1  = (const float*)d_in[13];
  const float* Wg2  = (const float*)d_in[14];

  float* out = (float*)d_out;
  float* xr  = out;                       // (3072,3072)
  float* h2  = out + 9437184;             // (3072,64)
  float* ie  = out + 9633792;             // (3072,96)
  float* cs  = out + 9928704;             // (3072,32)
  float* muo = out + 10027008;            // (3072,16)
  float* lvo = out + 10076160;            // (3072,16)

  float* w    = (float*)d_ws;
  float* buf0 = w;                        // h, then t1, then t2  (196608)
  float* buf1 = w + 196608;               // h_gat, then h1       (196608)
  float* ssrc = w + 393216;
  float* sdst = w + 396288;
  float* mrow = w + 399360;
  float* zrow = w + 402432;
  float* dis  = w + 405504;               // end: 408576 floats = 1.63 MB

  // ---- GAT: h = x^T @ W_gat
  hipMemsetAsync(buf0, 0, 196608 * sizeof(float), stream);
  k_xt_gemm<<<dim3(96, 4), 256, 0, stream>>>(x, Wgat, buf0);
  k_sd<<<768, 256, 0, stream>>>(buf0, agat, sdst, ssrc);
  k_stats<<<768, 256, 0, stream>>>(adj, sdst, ssrc, mrow, zrow);
  k_gat_av<<<192, 256, 0, stream>>>(buf0, adj, sdst, ssrc, mrow, zrow, buf1);
  // ---- VAE + diffusion fusion
  k_vae<<<192, 256, 0, stream>>>(buf1, eps, Wmu, bmu, Wlv, blv, Wdif, bdif, muo, lvo, cs);
  // ---- decoder
  k_dec<<<dim3(24, 96), 256, 0, stream>>>(cs, Wdec, bdec, xr);
  // ---- GCN stack
  k_deg<<<768, 256, 0, stream>>>(adj, dis);
  hipMemsetAsync(buf0, 0, 196608 * sizeof(float), stream);
  k_xt_gemm<<<dim3(96, 4), 256, 0, stream>>>(xr, Wg1, buf0);        // t1
  k_gcn_agg<<<192, 256, 0, stream>>>(buf0, adj, dis, buf1);         // h1
  k_h1w2<<<768, 256, 0, stream>>>(buf1, Wg2, buf0);                 // t2
  k_gcn_agg<<<192, 256, 0, stream>>>(buf0, adj, dis, h2);           // h2
  k_ie<<<1152, 256, 0, stream>>>(h2, cs, ie);
}

// Round 2
// 352.862 us; speedup vs baseline: 1.6617x; 1.6617x over previous
//
#include <hip/hip_runtime.h>
#include <math.h>

#define N 3072
#define H 64
#define CAUS 16
#define CSD 32
#define GAT_ALPHA 0.35f
#define SLICES 16
#define JSL (N / SLICES)  // 192
typedef unsigned long long u64;

// ---------------------------------------------------------------------------
// Pack adj row bits into u64 words (bit lane <-> column) + dis = (deg+1)^-1/2.
__global__ __launch_bounds__(256) void k_pack(const int* __restrict__ adj,
                                              u64* __restrict__ packed,
                                              float* __restrict__ dis) {
  int row = blockIdx.x * 4 + (threadIdx.x >> 6);
  int lane = threadIdx.x & 63;
  const int* ar = adj + (size_t)row * N;
  int deg = 0;
  for (int w = 0; w < 48; w++) {
    int v = ar[w * 64 + lane];
    u64 m = __ballot(v > 0);
    if (lane == 0) packed[(size_t)row * 48 + w] = m;
    deg += (v > 0) ? 1 : 0;
  }
  for (int off = 32; off; off >>= 1) deg += __shfl_xor(deg, off);
  if (lane == 0) dis[row] = rsqrtf((float)deg + 1.0f);
}

// ---------------------------------------------------------------------------
// out[g][f] += sum_{c in slice} X[c][g] * W[c][f]. X: NxN, W: Nx64.
// grid (48 g-tiles, 16 c-slices), 256 thr. 64x64 tile, float4 x float4.
__global__ __launch_bounds__(256) void k_xt_gemm(const float* __restrict__ X,
                                                 const float* __restrict__ W,
                                                 float* __restrict__ out) {
  __shared__ float xs[32 * 64];
  __shared__ float wsh[32 * 64];
  int t = threadIdx.x;
  int g0 = blockIdx.x * 64;
  int c0 = blockIdx.y * JSL;
  int gq = t & 15, fh = t >> 4;
  float4 acc0 = {0,0,0,0}, acc1 = {0,0,0,0}, acc2 = {0,0,0,0}, acc3 = {0,0,0,0};
  for (int kc = 0; kc < JSL; kc += 32) {
    int cbase = c0 + kc;
#pragma unroll
    for (int k = 0; k < 2; k++) {
      int lin = t + k * 256;
      int c = lin >> 4, q = lin & 15;
      ((float4*)xs)[lin] = ((const float4*)(X + (size_t)(cbase + c) * N + g0))[q];
      ((float4*)wsh)[lin] = ((const float4*)(W + (size_t)(cbase + c) * H))[q];
    }
    __syncthreads();
#pragma unroll 8
    for (int kk = 0; kk < 32; kk++) {
      float4 xv = ((float4*)xs)[kk * 16 + gq];
      float4 wv = ((float4*)wsh)[kk * 16 + fh];
      acc0.x += xv.x * wv.x; acc0.y += xv.x * wv.y; acc0.z += xv.x * wv.z; acc0.w += xv.x * wv.w;
      acc1.x += xv.y * wv.x; acc1.y += xv.y * wv.y; acc1.z += xv.y * wv.z; acc1.w += xv.y * wv.w;
      acc2.x += xv.z * wv.x; acc2.y += xv.z * wv.y; acc2.z += xv.z * wv.z; acc2.w += xv.z * wv.w;
      acc3.x += xv.w * wv.x; acc3.y += xv.w * wv.y; acc3.z += xv.w * wv.z; acc3.w += xv.w * wv.w;
    }
    __syncthreads();
  }
  float* b0 = out + (size_t)(g0 + gq * 4 + 0) * H + fh * 4;
  float* b1 = out + (size_t)(g0 + gq * 4 + 1) * H + fh * 4;
  float* b2 = out + (size_t)(g0 + gq * 4 + 2) * H + fh * 4;
  float* b3 = out + (size_t)(g0 + gq * 4 + 3) * H + fh * 4;
  atomicAdd(b0+0, acc0.x); atomicAdd(b0+1, acc0.y); atomicAdd(b0+2, acc0.z); atomicAdd(b0+3, acc0.w);
  atomicAdd(b1+0, acc1.x); atomicAdd(b1+1, acc1.y); atomicAdd(b1+2, acc1.z); atomicAdd(b1+3, acc1.w);
  atomicAdd(b2+0, acc2.x); atomicAdd(b2+1, acc2.y); atomicAdd(b2+2, acc2.z); atomicAdd(b2+3, acc2.w);
  atomicAdd(b3+0, acc3.x); atomicAdd(b3+1, acc3.y); atomicAdd(b3+2, acc3.z); atomicAdd(b3+3, acc3.w);
}

// ---------------------------------------------------------------------------
// s_dst[r] = h[r,:].a[0:64]; s_src[r] = h[r,:].a[64:128]. One wave per row.
__global__ __launch_bounds__(256) void k_sd(const float* __restrict__ h,
                                            const float* __restrict__ a,
                                            float* __restrict__ sdst,
                                            float* __restrict__ ssrc) {
  int row = blockIdx.x * 4 + (threadIdx.x >> 6);
  int lane = threadIdx.x & 63;
  float v = h[(size_t)row * H + lane];
  float d1 = v * a[lane];
  float d2 = v * a[H + lane];
  for (int off = 32; off; off >>= 1) {
    d1 += __shfl_xor(d1, off);
    d2 += __shfl_xor(d2, off);
  }
  if (lane == 0) { sdst[row] = d1; ssrc[row] = d2; }
}

// ---------------------------------------------------------------------------
// Branchless two-pass softmax stats from packed bits. One wave per row.
__global__ __launch_bounds__(256) void k_stats(const u64* __restrict__ packed,
                                               const float* __restrict__ sdst,
                                               const float* __restrict__ ssrc,
                                               float* __restrict__ mrow,
                                               float* __restrict__ zrow) {
  int row = blockIdx.x * 4 + (threadIdx.x >> 6);
  int lane = threadIdx.x & 63;
  const u64* pr = packed + (size_t)row * 48;
  float si = ssrc[row];
  float M = -INFINITY;
  for (int w = 0; w < 48; w++) {
    u64 wb = pr[w];
    float e = si + sdst[w * 64 + lane];
    e = e > 0.f ? e : GAT_ALPHA * e;
    if ((wb >> lane) & 1ULL) M = fmaxf(M, e);
  }
  for (int off = 32; off; off >>= 1) M = fmaxf(M, __shfl_xor(M, off));
  float S = 0.f;
  for (int w = 0; w < 48; w++) {
    u64 wb = pr[w];
    float e = si + sdst[w * 64 + lane];
    e = e > 0.f ? e : GAT_ALPHA * e;
    if ((wb >> lane) & 1ULL) S += __expf(e - M);
  }
  for (int off = 32; off; off >>= 1) S += __shfl_xor(S, off);
  if (lane == 0) { mrow[row] = M; zrow[row] = fmaxf(S, 1e-30f); }
}

// ---------------------------------------------------------------------------
// hacc[i,:] += sum_{j in slice} masked exp(e_ij - m_i) * h[j,:]
// grid (48 row-tiles, 16 j-slices). 64 rows x 64 cols per block.
__global__ __launch_bounds__(256) void k_gat_av(const float* __restrict__ h,
                                                const u64* __restrict__ packed,
                                                const float* __restrict__ sdst,
                                                const float* __restrict__ ssrc,
                                                const float* __restrict__ mrow,
                                                float* __restrict__ hacc) {
  __shared__ float4 hs4[64 * 16];
  __shared__ float wsm[64][65];
  __shared__ float ssrc_s[64], m_s[64];
  int t = threadIdx.x;
  int row0 = blockIdx.x * 64;
  if (t < 64) { ssrc_s[t] = ssrc[row0 + t]; m_s[t] = mrow[row0 + t]; }
  __syncthreads();
  int fq = t & 15, rr4 = t >> 4;
  int wrow = t >> 2, jq = (t & 3) * 16;
  float sv = ssrc_s[wrow], mv = m_s[wrow];
  float4 acc0 = {0,0,0,0}, acc1 = {0,0,0,0}, acc2 = {0,0,0,0}, acc3 = {0,0,0,0};
  int jend = blockIdx.y * JSL + JSL;
  for (int j0 = blockIdx.y * JSL; j0 < jend; j0 += 64) {
    const float4* H4 = (const float4*)h + (size_t)j0 * 16;
#pragma unroll
    for (int k = 0; k < 4; k++) hs4[t + k * 256] = H4[t + k * 256];
    u64 wb = packed[(size_t)(row0 + wrow) * 48 + (j0 >> 6)];
    const float4* sd4 = (const float4*)(sdst + j0 + jq);
    float4 s0 = sd4[0], s1 = sd4[1], s2 = sd4[2], s3 = sd4[3];
#define PR(val, q) { float e = sv + (val); e = e > 0.f ? e : GAT_ALPHA * e; \
  wsm[wrow][jq + (q)] = ((wb >> (jq + (q))) & 1ULL) ? __expf(e - mv) : 0.f; }
    PR(s0.x, 0) PR(s0.y, 1) PR(s0.z, 2) PR(s0.w, 3)
    PR(s1.x, 4) PR(s1.y, 5) PR(s1.z, 6) PR(s1.w, 7)
    PR(s2.x, 8) PR(s2.y, 9) PR(s2.z, 10) PR(s2.w, 11)
    PR(s3.x, 12) PR(s3.y, 13) PR(s3.z, 14) PR(s3.w, 15)
#undef PR
    __syncthreads();
#pragma unroll 8
    for (int jj = 0; jj < 64; jj++) {
      float4 hv = hs4[jj * 16 + fq];
      float w0 = wsm[rr4 * 4 + 0][jj], w1 = wsm[rr4 * 4 + 1][jj];
      float w2 = wsm[rr4 * 4 + 2][jj], w3 = wsm[rr4 * 4 + 3][jj];
      acc0.x += w0 * hv.x; acc0.y += w0 * hv.y; acc0.z += w0 * hv.z; acc0.w += w0 * hv.w;
      acc1.x += w1 * hv.x; acc1.y += w1 * hv.y; acc1.z += w1 * hv.z; acc1.w += w1 * hv.w;
      acc2.x += w2 * hv.x; acc2.y += w2 * hv.y; acc2.z += w2 * hv.z; acc2.w += w2 * hv.w;
      acc3.x += w3 * hv.x; acc3.y += w3 * hv.y; acc3.z += w3 * hv.z; acc3.w += w3 * hv.w;
    }
    __syncthreads();
  }
  float* b0 = hacc + (size_t)(row0 + rr4 * 4 + 0) * H + fq * 4;
  float* b1 = hacc + (size_t)(row0 + rr4 * 4 + 1) * H + fq * 4;
  float* b2 = hacc + (size_t)(row0 + rr4 * 4 + 2) * H + fq * 4;
  float* b3 = hacc + (size_t)(row0 + rr4 * 4 + 3) * H + fq * 4;
  atomicAdd(b0+0, acc0.x); atomicAdd(b0+1, acc0.y); atomicAdd(b0+2, acc0.z); atomicAdd(b0+3, acc0.w);
  atomicAdd(b1+0, acc1.x); atomicAdd(b1+1, acc1.y); atomicAdd(b1+2, acc1.z); atomicAdd(b1+3, acc1.w);
  atomicAdd(b2+0, acc2.x); atomicAdd(b2+1, acc2.y); atomicAdd(b2+2, acc2.z); atomicAdd(b2+3, acc2.w);
  atomicAdd(b3+0, acc3.x); atomicAdd(b3+1, acc3.y); atomicAdd(b3+2, acc3.z); atomicAdd(b3+3, acc3.w);
}

// ---------------------------------------------------------------------------
// acc[i,:] += sum_{j in slice} (bit_ij + delta_ij)*dis[j] * tin[j,:]
__global__ __launch_bounds__(256) void k_gcn_agg(const float* __restrict__ tin,
                                                 const u64* __restrict__ packed,
                                                 const float* __restrict__ dis,
                                                 float* __restrict__ oacc) {
  __shared__ float4 hs4[64 * 16];
  __shared__ float wsm[64][65];
  int t = threadIdx.x;
  int row0 = blockIdx.x * 64;
  int fq = t & 15, rr4 = t >> 4;
  int wrow = t >> 2, jq = (t & 3) * 16;
  float4 acc0 = {0,0,0,0}, acc1 = {0,0,0,0}, acc2 = {0,0,0,0}, acc3 = {0,0,0,0};
  int jend = blockIdx.y * JSL + JSL;
  for (int j0 = blockIdx.y * JSL; j0 < jend; j0 += 64) {
    const float4* T4 = (const float4*)tin + (size_t)j0 * 16;
#pragma unroll
    for (int k = 0; k < 4; k++) hs4[t + k * 256] = T4[t + k * 256];
    u64 wb = packed[(size_t)(row0 + wrow) * 48 + (j0 >> 6)];
    const float4* dd4 = (const float4*)(dis + j0 + jq);
    float4 d0 = dd4[0], d1 = dd4[1], d2 = dd4[2], d3 = dd4[3];
#define PRG(val, q) { float cnt = (float)((wb >> (jq + (q))) & 1ULL) + \
  ((row0 + wrow) == (j0 + jq + (q)) ? 1.f : 0.f); wsm[wrow][jq + (q)] = cnt * (val); }
    PRG(d0.x, 0) PRG(d0.y, 1) PRG(d0.z, 2) PRG(d0.w, 3)
    PRG(d1.x, 4) PRG(d1.y, 5) PRG(d1.z, 6) PRG(d1.w, 7)
    PRG(d2.x, 8) PRG(d2.y, 9) PRG(d2.z, 10) PRG(d2.w, 11)
    PRG(d3.x, 12) PRG(d3.y, 13) PRG(d3.z, 14) PRG(d3.w, 15)
#undef PRG
    __syncthreads();
#pragma unroll 8
    for (int jj = 0; jj < 64; jj++) {
      float4 hv = hs4[jj * 16 + fq];
      float w0 = wsm[rr4 * 4 + 0][jj], w1 = wsm[rr4 * 4 + 1][jj];
      float w2 = wsm[rr4 * 4 + 2][jj], w3 = wsm[rr4 * 4 + 3][jj];
      acc0.x += w0 * hv.x; acc0.y += w0 * hv.y; acc0.z += w0 * hv.z; acc0.w += w0 * hv.w;
      acc1.x += w1 * hv.x; acc1.y += w1 * hv.y; acc1.z += w1 * hv.z; acc1.w += w1 * hv.w;
      acc2.x += w2 * hv.x; acc2.y += w2 * hv.y; acc2.z += w2 * hv.z; acc2.w += w2 * hv.w;
      acc3.x += w3 * hv.x; acc3.y += w3 * hv.y; acc3.z += w3 * hv.z; acc3.w += w3 * hv.w;
    }
    __syncthreads();
  }
  float* b0 = oacc + (size_t)(row0 + rr4 * 4 + 0) * H + fq * 4;
  float* b1 = oacc + (size_t)(row0 + rr4 * 4 + 1) * H + fq * 4;
  float* b2 = oacc + (size_t)(row0 + rr4 * 4 + 2) * H + fq * 4;
  float* b3 = oacc + (size_t)(row0 + rr4 * 4 + 3) * H + fq * 4;
  atomicAdd(b0+0, acc0.x); atomicAdd(b0+1, acc0.y); atomicAdd(b0+2, acc0.z); atomicAdd(b0+3, acc0.w);
  atomicAdd(b1+0, acc1.x); atomicAdd(b1+1, acc1.y); atomicAdd(b1+2, acc1.z); atomicAdd(b1+3, acc1.w);
  atomicAdd(b2+0, acc2.x); atomicAdd(b2+1, acc2.y); atomicAdd(b2+2, acc2.z); atomicAdd(b2+3, acc2.w);
  atomicAdd(b3+0, acc3.x); atomicAdd(b3+1, acc3.y); atomicAdd(b3+2, acc3.z); atomicAdd(b3+3, acc3.w);
}

// ---------------------------------------------------------------------------
// VAE + diffusion fusion; finalizes h_gat = elu(hacc/Z) on load; writes cs & ie.
__global__ __launch_bounds__(256) void k_vae(const float* __restrict__ hacc,
                                             const float* __restrict__ zrow,
                                             const float* __restrict__ eps,
                                             const float* __restrict__ Wmu,
                                             const float* __restrict__ bmu,
                                             const float* __restrict__ Wlv,
                                             const float* __restrict__ blv,
                                             const float* __restrict__ Wd,
                                             const float* __restrict__ bd,
                                             float* __restrict__ mu_o,
                                             float* __restrict__ lv_o,
                                             float* __restrict__ cs_o,
                                             float* __restrict__ ie) {
  __shared__ float hs[16][65];
  __shared__ float zs[16][17];
  __shared__ float wmu_s[64 * 16];
  __shared__ float wlv_s[64 * 16];
  __shared__ float wd_s[80 * 32];
  int t = threadIdx.x;
  int row0 = blockIdx.x * 16;
#pragma unroll
  for (int k = 0; k < 4; k++) {
    int lin = t + k * 256;
    int rr = lin >> 6;
    float v = hacc[(size_t)row0 * H + lin] / zrow[row0 + rr];
    hs[rr][lin & 63] = v > 0.f ? v : __expf(v) - 1.f;
    wmu_s[lin] = Wmu[lin];
    wlv_s[lin] = Wlv[lin];
  }
#pragma unroll
  for (int k = 0; k < 10; k++) {
    int lin = t + k * 256;
    wd_s[lin] = Wd[lin];
  }
  __syncthreads();
  int r = t >> 4, kk = t & 15;
  float mu = bmu[kk], lv = blv[kk];
#pragma unroll 8
  for (int l = 0; l < 64; l++) {
    float hv = hs[r][l];
    mu += hv * wmu_s[l * 16 + kk];
    lv += hv * wlv_s[l * 16 + kk];
  }
  float z = mu + eps[(size_t)(row0 + r) * CAUS + kk] * __expf(0.5f * lv);
  mu_o[(size_t)(row0 + r) * CAUS + kk] = mu;
  lv_o[(size_t)(row0 + r) * CAUS + kk] = lv;
  zs[r][kk] = z;
  __syncthreads();
#pragma unroll
  for (int p = 0; p < 2; p++) {
    int lin = t + p * 256;
    int rr = lin >> 5, c = lin & 31;
    float acc = bd[c];
#pragma unroll 4
    for (int q = 0; q < 16; q++) acc += zs[rr][q] * wd_s[q * 32 + c];
#pragma unroll 8
    for (int l = 0; l < 64; l++) acc += hs[rr][l] * wd_s[(16 + l) * 32 + c];
    float v = fmaxf(acc, 0.f);
    cs_o[(size_t)(row0 + rr) * CSD + c] = v;
    ie[(size_t)(row0 + rr) * 96 + 64 + c] = v;
  }
}

// ---------------------------------------------------------------------------
// x_recon = sigmoid(cs @ W_dec + b_dec). 32 rows x 128 cols per block.
__global__ __launch_bounds__(256) void k_dec(const float* __restrict__ cs,
                                             const float* __restrict__ Wdec,
                                             const float* __restrict__ bdec,
                                             float* __restrict__ xr) {
  __shared__ float cs_s[32][33];
  __shared__ float4 wd4[32 * 32];
  int t = threadIdx.x;
  int c0 = blockIdx.x * 128;
  int row0 = blockIdx.y * 32;
#pragma unroll
  for (int k = 0; k < 4; k++) {
    int lin = t + k * 256;
    cs_s[lin >> 5][lin & 31] = cs[(size_t)(row0 + (lin >> 5)) * CSD + (lin & 31)];
    int kr = lin >> 5, c4 = lin & 31;
    wd4[lin] = ((const float4*)(Wdec + (size_t)kr * N + c0))[c4];
  }
  __syncthreads();
  int rq = t >> 5, cq = t & 31;
  float4 acc[4];
#pragma unroll
  for (int ri = 0; ri < 4; ri++) acc[ri] = make_float4(0.f, 0.f, 0.f, 0.f);
#pragma unroll 8
  for (int k = 0; k < 32; k++) {
    float4 wv = wd4[k * 32 + cq];
#pragma unroll
    for (int ri = 0; ri < 4; ri++) {
      float cv = cs_s[rq * 4 + ri][k];
      acc[ri].x += cv * wv.x; acc[ri].y += cv * wv.y;
      acc[ri].z += cv * wv.z; acc[ri].w += cv * wv.w;
    }
  }
  float4 bv = ((const float4*)(bdec + c0))[cq];
#pragma unroll
  for (int ri = 0; ri < 4; ri++) {
    float4 v = acc[ri];
    v.x = 1.f / (1.f + __expf(-(v.x + bv.x)));
    v.y = 1.f / (1.f + __expf(-(v.y + bv.y)));
    v.z = 1.f / (1.f + __expf(-(v.z + bv.z)));
    v.w = 1.f / (1.f + __expf(-(v.w + bv.w)));
    ((float4*)(xr + (size_t)(row0 + rq * 4 + ri) * N + c0))[cq] = v;
  }
}

// ---------------------------------------------------------------------------
// t2 = relu(h1acc*dis) @ W2. 4 rows/block.
__global__ __launch_bounds__(256) void k_h1w2(const float* __restrict__ h1acc,
                                              const float* __restrict__ dis,
                                              const float* __restrict__ W2,
                                              float* __restrict__ t2) {
  __shared__ float w2s[64 * 64];
  __shared__ float hs[4][65];
  int t = threadIdx.x;
  int row0 = blockIdx.x * 4;
#pragma unroll
  for (int k = 0; k < 16; k++) w2s[t + k * 256] = W2[t + k * 256];
  {
    int rr = t >> 6;
    hs[rr][t & 63] = fmaxf(h1acc[(size_t)row0 * H + t] * dis[row0 + rr], 0.f);
  }
  __syncthreads();
  int r = t >> 6, f = t & 63;
  float acc = 0.f;
#pragma unroll 8
  for (int l = 0; l < 64; l++) acc += hs[r][l] * w2s[l * 64 + f];
  t2[(size_t)(row0 + r) * H + f] = acc;
}

// ---------------------------------------------------------------------------
// h2 = relu(h2acc*dis); also writes ie[:, :64].
__global__ __launch_bounds__(256) void k_fin2(const float* __restrict__ h2acc,
                                              const float* __restrict__ dis,
                                              float* __restrict__ h2,
                                              float* __restrict__ ie) {
  int idx = blockIdx.x * 256 + threadIdx.x;
  int row = idx >> 6, f = idx & 63;
  float v = fmaxf(h2acc[idx] * dis[row], 0.f);
  h2[idx] = v;
  ie[(size_t)row * 96 + f] = v;
}

// ---------------------------------------------------------------------------
extern "C" void kernel_launch(void* const* d_in, const int* in_sizes, int n_in,
                              void* d_out, int out_size, void* d_ws, size_t ws_size,
                              hipStream_t stream) {
  const float* x    = (const float*)d_in[0];
  const int*   adj  = (const int*)d_in[1];
  const float* eps  = (const float*)d_in[2];
  const float* Wgat = (const float*)d_in[3];
  const float* agat = (const float*)d_in[4];
  const float* Wmu  = (const float*)d_in[5];
  const float* bmu  = (const float*)d_in[6];
  const float* Wlv  = (const float*)d_in[7];
  const float* blv  = (const float*)d_in[8];
  const float* Wdif = (const float*)d_in[9];
  const float* bdif = (const float*)d_in[10];
  const float* Wdec = (const float*)d_in[11];
  const float* bdec = (const float*)d_in[12];
  const float* Wg1  = (const float*)d_in[13];
  const float* Wg2  = (const float*)d_in[14];

  float* out = (float*)d_out;
  float* xr  = out;                       // (3072,3072)
  float* h2  = out + 9437184;             // (3072,64)
  float* ie  = out + 9633792;             // (3072,96)
  float* cs  = out + 9928704;             // (3072,32)
  float* muo = out + 10027008;            // (3072,16)
  float* lvo = out + 10076160;            // (3072,16)

  u64*   packed = (u64*)d_ws;             // 3072*48 u64 = 1.18 MB
  float* wf   = (float*)d_ws + 294912;
  float* buf0 = wf;                       // h, then t1acc, then h2acc (196608)
  float* buf1 = wf + 196608;              // hacc, then t2              (196608)
  float* buf2 = wf + 393216;              // h1acc                      (196608)
  float* ssrc = wf + 589824;
  float* sdst = wf + 592896;
  float* mrow = wf + 595968;
  float* zrow = wf + 599040;
  float* dis  = wf + 602112;              // end: 605184 floats (3.44 MB total)

  // ---- adjacency pack + degrees
  k_pack<<<768, 256, 0, stream>>>(adj, packed, dis);
  // ---- GAT: h = x^T @ W_gat
  hipMemsetAsync(buf0, 0, 196608 * sizeof(float), stream);
  k_xt_gemm<<<dim3(48, SLICES), 256, 0, stream>>>(x, Wgat, buf0);
  k_sd<<<768, 256, 0, stream>>>(buf0, agat, sdst, ssrc);
  k_stats<<<768, 256, 0, stream>>>(packed, sdst, ssrc, mrow, zrow);
  hipMemsetAsync(buf1, 0, 196608 * sizeof(float), stream);
  k_gat_av<<<dim3(48, SLICES), 256, 0, stream>>>(buf0, packed, sdst, ssrc, mrow, buf1);
  // ---- VAE + diffusion fusion (finalizes h_gat on load)
  k_vae<<<192, 256, 0, stream>>>(buf1, zrow, eps, Wmu, bmu, Wlv, blv, Wdif, bdif,
                                 muo, lvo, cs, ie);
  // ---- decoder
  k_dec<<<dim3(24, 96), 256, 0, stream>>>(cs, Wdec, bdec, xr);
  // ---- GCN stack
  hipMemsetAsync(buf0, 0, 196608 * sizeof(float), stream);
  k_xt_gemm<<<dim3(48, SLICES), 256, 0, stream>>>(xr, Wg1, buf0);            // t1acc
  hipMemsetAsync(buf2, 0, 196608 * sizeof(float), stream);
  k_gcn_agg<<<dim3(48, SLICES), 256, 0, stream>>>(buf0, packed, dis, buf2);  // h1acc
  k_h1w2<<<768, 256, 0, stream>>>(buf2, dis, Wg2, buf1);                     // t2
  hipMemsetAsync(buf0, 0, 196608 * sizeof(float), stream);
  k_gcn_agg<<<dim3(48, SLICES), 256, 0, stream>>>(buf1, packed, dis, buf0);  // h2acc
  k_fin2<<<768, 256, 0, stream>>>(buf0, dis, h2, ie);
}

// Round 3
// 217.650 us; speedup vs baseline: 2.6940x; 1.6212x over previous
//
#include <hip/hip_runtime.h>
#include <math.h>

#define N 3072
#define H 64
#define CAUS 16
#define CSD 32
#define GAT_ALPHA 0.35f
#define SLICES 16
#define JSL (N / SLICES)  // 192
#define NH (N * H)        // 196608
typedef unsigned long long u64;

// ---------------------------------------------------------------------------
// Pack adj row bits into u64 words (bit lane <-> column) + dis = (deg+1)^-1/2.
__global__ __launch_bounds__(256) void k_pack(const int* __restrict__ adj,
                                              u64* __restrict__ packed,
                                              float* __restrict__ dis) {
  int row = blockIdx.x * 4 + (threadIdx.x >> 6);
  int lane = threadIdx.x & 63;
  const int* ar = adj + (size_t)row * N;
  int deg = 0;
  for (int w = 0; w < 48; w++) {
    int v = ar[w * 64 + lane];
    u64 m = __ballot(v > 0);
    if (lane == 0) packed[(size_t)row * 48 + w] = m;
    deg += (v > 0) ? 1 : 0;
  }
  for (int off = 32; off; off >>= 1) deg += __shfl_xor(deg, off);
  if (lane == 0) dis[row] = rsqrtf((float)deg + 1.0f);
}

// ---------------------------------------------------------------------------
// out[g][f] (+)= sum_{c in slice} X[c][g] * W[c][f]. X: NxN, W: Nx64.
// PARTIAL=1: plain stores into out + slice*NH. PARTIAL=0: atomicAdd (needs memset).
template <int PARTIAL>
__global__ __launch_bounds__(256) void k_xt_gemm(const float* __restrict__ X,
                                                 const float* __restrict__ W,
                                                 float* __restrict__ out) {
  __shared__ float xs[32 * 64];
  __shared__ float wsh[32 * 64];
  int t = threadIdx.x;
  int g0 = blockIdx.x * 64;
  int c0 = blockIdx.y * JSL;
  int gq = t & 15, fh = t >> 4;
  float4 acc0 = {0,0,0,0}, acc1 = {0,0,0,0}, acc2 = {0,0,0,0}, acc3 = {0,0,0,0};
  for (int kc = 0; kc < JSL; kc += 32) {
    int cbase = c0 + kc;
#pragma unroll
    for (int k = 0; k < 2; k++) {
      int lin = t + k * 256;
      int c = lin >> 4, q = lin & 15;
      ((float4*)xs)[lin] = ((const float4*)(X + (size_t)(cbase + c) * N + g0))[q];
      ((float4*)wsh)[lin] = ((const float4*)(W + (size_t)(cbase + c) * H))[q];
    }
    __syncthreads();
#pragma unroll 8
    for (int kk = 0; kk < 32; kk++) {
      float4 xv = ((float4*)xs)[kk * 16 + gq];
      float4 wv = ((float4*)wsh)[kk * 16 + fh];
      acc0.x += xv.x * wv.x; acc0.y += xv.x * wv.y; acc0.z += xv.x * wv.z; acc0.w += xv.x * wv.w;
      acc1.x += xv.y * wv.x; acc1.y += xv.y * wv.y; acc1.z += xv.y * wv.z; acc1.w += xv.y * wv.w;
      acc2.x += xv.z * wv.x; acc2.y += xv.z * wv.y; acc2.z += xv.z * wv.z; acc2.w += xv.z * wv.w;
      acc3.x += xv.w * wv.x; acc3.y += xv.w * wv.y; acc3.z += xv.w * wv.z; acc3.w += xv.w * wv.w;
    }
    __syncthreads();
  }
  if (PARTIAL) {
    float* ob = out + (size_t)blockIdx.y * NH;
    ((float4*)(ob + (size_t)(g0 + gq * 4 + 0) * H))[fh] = acc0;
    ((float4*)(ob + (size_t)(g0 + gq * 4 + 1) * H))[fh] = acc1;
    ((float4*)(ob + (size_t)(g0 + gq * 4 + 2) * H))[fh] = acc2;
    ((float4*)(ob + (size_t)(g0 + gq * 4 + 3) * H))[fh] = acc3;
  } else {
    float* b0 = out + (size_t)(g0 + gq * 4 + 0) * H + fh * 4;
    float* b1 = out + (size_t)(g0 + gq * 4 + 1) * H + fh * 4;
    float* b2 = out + (size_t)(g0 + gq * 4 + 2) * H + fh * 4;
    float* b3 = out + (size_t)(g0 + gq * 4 + 3) * H + fh * 4;
    atomicAdd(b0+0, acc0.x); atomicAdd(b0+1, acc0.y); atomicAdd(b0+2, acc0.z); atomicAdd(b0+3, acc0.w);
    atomicAdd(b1+0, acc1.x); atomicAdd(b1+1, acc1.y); atomicAdd(b1+2, acc1.z); atomicAdd(b1+3, acc1.w);
    atomicAdd(b2+0, acc2.x); atomicAdd(b2+1, acc2.y); atomicAdd(b2+2, acc2.z); atomicAdd(b2+3, acc2.w);
    atomicAdd(b3+0, acc3.x); atomicAdd(b3+1, acc3.y); atomicAdd(b3+2, acc3.z); atomicAdd(b3+3, acc3.w);
  }
}

// ---------------------------------------------------------------------------
// Reduce nparts partial h buffers -> h, fused with s_dst/s_src dot products.
__global__ __launch_bounds__(256) void k_reduce_sd(const float* __restrict__ src,
                                                   int nparts,
                                                   const float* __restrict__ a,
                                                   float* __restrict__ h,
                                                   float* __restrict__ sdst,
                                                   float* __restrict__ ssrc) {
  int row = blockIdx.x * 4 + (threadIdx.x >> 6);
  int lane = threadIdx.x & 63;
  size_t off = (size_t)row * H + lane;
  float v = 0.f;
  for (int p = 0; p < nparts; p++) v += src[(size_t)p * NH + off];
  h[off] = v;
  float d1 = v * a[lane];
  float d2 = v * a[H + lane];
  for (int o = 32; o; o >>= 1) {
    d1 += __shfl_xor(d1, o);
    d2 += __shfl_xor(d2, o);
  }
  if (lane == 0) { sdst[row] = d1; ssrc[row] = d2; }
}

// ---------------------------------------------------------------------------
// Generic 16-way float4 partial reduce: dst = sum_p src[p].
__global__ __launch_bounds__(256) void k_reduce(const float4* __restrict__ src,
                                                int nparts,
                                                float4* __restrict__ dst) {
  int idx = blockIdx.x * 256 + threadIdx.x;  // grid 192 -> 49152 float4
  float4 v = {0, 0, 0, 0};
  for (int p = 0; p < nparts; p++) {
    float4 u = src[(size_t)p * (NH / 4) + idx];
    v.x += u.x; v.y += u.y; v.z += u.z; v.w += u.w;
  }
  dst[idx] = v;
}

// ---------------------------------------------------------------------------
// Branchless two-pass softmax stats from packed bits. One wave per row.
__global__ __launch_bounds__(256) void k_stats(const u64* __restrict__ packed,
                                               const float* __restrict__ sdst,
                                               const float* __restrict__ ssrc,
                                               float* __restrict__ mrow,
                                               float* __restrict__ zrow) {
  int row = blockIdx.x * 4 + (threadIdx.x >> 6);
  int lane = threadIdx.x & 63;
  const u64* pr = packed + (size_t)row * 48;
  float si = ssrc[row];
  float M = -INFINITY;
  for (int w = 0; w < 48; w++) {
    u64 wb = pr[w];
    float e = si + sdst[w * 64 + lane];
    e = e > 0.f ? e : GAT_ALPHA * e;
    if ((wb >> lane) & 1ULL) M = fmaxf(M, e);
  }
  for (int off = 32; off; off >>= 1) M = fmaxf(M, __shfl_xor(M, off));
  float S = 0.f;
  for (int w = 0; w < 48; w++) {
    u64 wb = pr[w];
    float e = si + sdst[w * 64 + lane];
    e = e > 0.f ? e : GAT_ALPHA * e;
    if ((wb >> lane) & 1ULL) S += __expf(e - M);
  }
  for (int off = 32; off; off >>= 1) S += __shfl_xor(S, off);
  if (lane == 0) { mrow[row] = M; zrow[row] = fmaxf(S, 1e-30f); }
}

// ---------------------------------------------------------------------------
// hacc[i,:] (+)= sum_{j in slice} masked exp(e_ij - m_i) * h[j,:]
template <int PARTIAL>
__global__ __launch_bounds__(256) void k_gat_av(const float* __restrict__ h,
                                                const u64* __restrict__ packed,
                                                const float* __restrict__ sdst,
                                                const float* __restrict__ ssrc,
                                                const float* __restrict__ mrow,
                                                float* __restrict__ hacc) {
  __shared__ float4 hs4[64 * 16];
  __shared__ float wsm[64][65];
  __shared__ float ssrc_s[64], m_s[64];
  int t = threadIdx.x;
  int row0 = blockIdx.x * 64;
  if (t < 64) { ssrc_s[t] = ssrc[row0 + t]; m_s[t] = mrow[row0 + t]; }
  __syncthreads();
  int fq = t & 15, rr4 = t >> 4;
  int wrow = t >> 2, jq = (t & 3) * 16;
  float sv = ssrc_s[wrow], mv = m_s[wrow];
  float4 acc0 = {0,0,0,0}, acc1 = {0,0,0,0}, acc2 = {0,0,0,0}, acc3 = {0,0,0,0};
  int jend = blockIdx.y * JSL + JSL;
  for (int j0 = blockIdx.y * JSL; j0 < jend; j0 += 64) {
    const float4* H4 = (const float4*)h + (size_t)j0 * 16;
#pragma unroll
    for (int k = 0; k < 4; k++) hs4[t + k * 256] = H4[t + k * 256];
    u64 wb = packed[(size_t)(row0 + wrow) * 48 + (j0 >> 6)];
    const float4* sd4 = (const float4*)(sdst + j0 + jq);
    float4 s0 = sd4[0], s1 = sd4[1], s2 = sd4[2], s3 = sd4[3];
#define PR(val, q) { float e = sv + (val); e = e > 0.f ? e : GAT_ALPHA * e; \
  wsm[wrow][jq + (q)] = ((wb >> (jq + (q))) & 1ULL) ? __expf(e - mv) : 0.f; }
    PR(s0.x, 0) PR(s0.y, 1) PR(s0.z, 2) PR(s0.w, 3)
    PR(s1.x, 4) PR(s1.y, 5) PR(s1.z, 6) PR(s1.w, 7)
    PR(s2.x, 8) PR(s2.y, 9) PR(s2.z, 10) PR(s2.w, 11)
    PR(s3.x, 12) PR(s3.y, 13) PR(s3.z, 14) PR(s3.w, 15)
#undef PR
    __syncthreads();
#pragma unroll 8
    for (int jj = 0; jj < 64; jj++) {
      float4 hv = hs4[jj * 16 + fq];
      float w0 = wsm[rr4 * 4 + 0][jj], w1 = wsm[rr4 * 4 + 1][jj];
      float w2 = wsm[rr4 * 4 + 2][jj], w3 = wsm[rr4 * 4 + 3][jj];
      acc0.x += w0 * hv.x; acc0.y += w0 * hv.y; acc0.z += w0 * hv.z; acc0.w += w0 * hv.w;
      acc1.x += w1 * hv.x; acc1.y += w1 * hv.y; acc1.z += w1 * hv.z; acc1.w += w1 * hv.w;
      acc2.x += w2 * hv.x; acc2.y += w2 * hv.y; acc2.z += w2 * hv.z; acc2.w += w2 * hv.w;
      acc3.x += w3 * hv.x; acc3.y += w3 * hv.y; acc3.z += w3 * hv.z; acc3.w += w3 * hv.w;
    }
    __syncthreads();
  }
  if (PARTIAL) {
    float* ob = hacc + (size_t)blockIdx.y * NH;
    ((float4*)(ob + (size_t)(row0 + rr4 * 4 + 0) * H))[fq] = acc0;
    ((float4*)(ob + (size_t)(row0 + rr4 * 4 + 1) * H))[fq] = acc1;
    ((float4*)(ob + (size_t)(row0 + rr4 * 4 + 2) * H))[fq] = acc2;
    ((float4*)(ob + (size_t)(row0 + rr4 * 4 + 3) * H))[fq] = acc3;
  } else {
    float* b0 = hacc + (size_t)(row0 + rr4 * 4 + 0) * H + fq * 4;
    float* b1 = hacc + (size_t)(row0 + rr4 * 4 + 1) * H + fq * 4;
    float* b2 = hacc + (size_t)(row0 + rr4 * 4 + 2) * H + fq * 4;
    float* b3 = hacc + (size_t)(row0 + rr4 * 4 + 3) * H + fq * 4;
    atomicAdd(b0+0, acc0.x); atomicAdd(b0+1, acc0.y); atomicAdd(b0+2, acc0.z); atomicAdd(b0+3, acc0.w);
    atomicAdd(b1+0, acc1.x); atomicAdd(b1+1, acc1.y); atomicAdd(b1+2, acc1.z); atomicAdd(b1+3, acc1.w);
    atomicAdd(b2+0, acc2.x); atomicAdd(b2+1, acc2.y); atomicAdd(b2+2, acc2.z); atomicAdd(b2+3, acc2.w);
    atomicAdd(b3+0, acc3.x); atomicAdd(b3+1, acc3.y); atomicAdd(b3+2, acc3.z); atomicAdd(b3+3, acc3.w);
  }
}

// ---------------------------------------------------------------------------
// oacc[i,:] (+)= sum_{j in slice} (bit_ij + delta_ij)*dis[j] * tin[j,:]
template <int PARTIAL>
__global__ __launch_bounds__(256) void k_gcn_agg(const float* __restrict__ tin,
                                                 const u64* __restrict__ packed,
                                                 const float* __restrict__ dis,
                                                 float* __restrict__ oacc) {
  __shared__ float4 hs4[64 * 16];
  __shared__ float wsm[64][65];
  int t = threadIdx.x;
  int row0 = blockIdx.x * 64;
  int fq = t & 15, rr4 = t >> 4;
  int wrow = t >> 2, jq = (t & 3) * 16;
  float4 acc0 = {0,0,0,0}, acc1 = {0,0,0,0}, acc2 = {0,0,0,0}, acc3 = {0,0,0,0};
  int jend = blockIdx.y * JSL + JSL;
  for (int j0 = blockIdx.y * JSL; j0 < jend; j0 += 64) {
    const float4* T4 = (const float4*)tin + (size_t)j0 * 16;
#pragma unroll
    for (int k = 0; k < 4; k++) hs4[t + k * 256] = T4[t + k * 256];
    u64 wb = packed[(size_t)(row0 + wrow) * 48 + (j0 >> 6)];
    const float4* dd4 = (const float4*)(dis + j0 + jq);
    float4 d0 = dd4[0], d1 = dd4[1], d2 = dd4[2], d3 = dd4[3];
#define PRG(val, q) { float cnt = (float)((wb >> (jq + (q))) & 1ULL) + \
  ((row0 + wrow) == (j0 + jq + (q)) ? 1.f : 0.f); wsm[wrow][jq + (q)] = cnt * (val); }
    PRG(d0.x, 0) PRG(d0.y, 1) PRG(d0.z, 2) PRG(d0.w, 3)
    PRG(d1.x, 4) PRG(d1.y, 5) PRG(d1.z, 6) PRG(d1.w, 7)
    PRG(d2.x, 8) PRG(d2.y, 9) PRG(d2.z, 10) PRG(d2.w, 11)
    PRG(d3.x, 12) PRG(d3.y, 13) PRG(d3.z, 14) PRG(d3.w, 15)
#undef PRG
    __syncthreads();
#pragma unroll 8
    for (int jj = 0; jj < 64; jj++) {
      float4 hv = hs4[jj * 16 + fq];
      float w0 = wsm[rr4 * 4 + 0][jj], w1 = wsm[rr4 * 4 + 1][jj];
      float w2 = wsm[rr4 * 4 + 2][jj], w3 = wsm[rr4 * 4 + 3][jj];
      acc0.x += w0 * hv.x; acc0.y += w0 * hv.y; acc0.z += w0 * hv.z; acc0.w += w0 * hv.w;
      acc1.x += w1 * hv.x; acc1.y += w1 * hv.y; acc1.z += w1 * hv.z; acc1.w += w1 * hv.w;
      acc2.x += w2 * hv.x; acc2.y += w2 * hv.y; acc2.z += w2 * hv.z; acc2.w += w2 * hv.w;
      acc3.x += w3 * hv.x; acc3.y += w3 * hv.y; acc3.z += w3 * hv.z; acc3.w += w3 * hv.w;
    }
    __syncthreads();
  }
  if (PARTIAL) {
    float* ob = oacc + (size_t)blockIdx.y * NH;
    ((float4*)(ob + (size_t)(row0 + rr4 * 4 + 0) * H))[fq] = acc0;
    ((float4*)(ob + (size_t)(row0 + rr4 * 4 + 1) * H))[fq] = acc1;
    ((float4*)(ob + (size_t)(row0 + rr4 * 4 + 2) * H))[fq] = acc2;
    ((float4*)(ob + (size_t)(row0 + rr4 * 4 + 3) * H))[fq] = acc3;
  } else {
    float* b0 = oacc + (size_t)(row0 + rr4 * 4 + 0) * H + fq * 4;
    float* b1 = oacc + (size_t)(row0 + rr4 * 4 + 1) * H + fq * 4;
    float* b2 = oacc + (size_t)(row0 + rr4 * 4 + 2) * H + fq * 4;
    float* b3 = oacc + (size_t)(row0 + rr4 * 4 + 3) * H + fq * 4;
    atomicAdd(b0+0, acc0.x); atomicAdd(b0+1, acc0.y); atomicAdd(b0+2, acc0.z); atomicAdd(b0+3, acc0.w);
    atomicAdd(b1+0, acc1.x); atomicAdd(b1+1, acc1.y); atomicAdd(b1+2, acc1.z); atomicAdd(b1+3, acc1.w);
    atomicAdd(b2+0, acc2.x); atomicAdd(b2+1, acc2.y); atomicAdd(b2+2, acc2.z); atomicAdd(b2+3, acc2.w);
    atomicAdd(b3+0, acc3.x); atomicAdd(b3+1, acc3.y); atomicAdd(b3+2, acc3.z); atomicAdd(b3+3, acc3.w);
  }
}

// ---------------------------------------------------------------------------
// VAE + diffusion fusion; sums nparts hacc partials, finalizes elu(./Z) on load.
__global__ __launch_bounds__(256) void k_vae(const float* __restrict__ hacc,
                                             int nparts,
                                             const float* __restrict__ zrow,
                                             const float* __restrict__ eps,
                                             const float* __restrict__ Wmu,
                                             const float* __restrict__ bmu,
                                             const float* __restrict__ Wlv,
                                             const float* __restrict__ blv,
                                             const float* __restrict__ Wd,
                                             const float* __restrict__ bd,
                                             float* __restrict__ mu_o,
                                             float* __restrict__ lv_o,
                                             float* __restrict__ cs_o,
                                             float* __restrict__ ie) {
  __shared__ float hs[16][65];
  __shared__ float zs[16][17];
  __shared__ float wmu_s[64 * 16];
  __shared__ float wlv_s[64 * 16];
  __shared__ float wd_s[80 * 32];
  int t = threadIdx.x;
  int row0 = blockIdx.x * 16;
  {
    const float4* g4 = (const float4*)(hacc + (size_t)row0 * H);
    float4 v = {0, 0, 0, 0};
    for (int p = 0; p < nparts; p++) {
      float4 u = g4[(size_t)p * (NH / 4) + t];
      v.x += u.x; v.y += u.y; v.z += u.z; v.w += u.w;
    }
    int rr = t >> 4, c0 = (t & 15) * 4;
    float zi = 1.0f / zrow[row0 + rr];
    float e0 = v.x * zi, e1 = v.y * zi, e2 = v.z * zi, e3 = v.w * zi;
    hs[rr][c0 + 0] = e0 > 0.f ? e0 : __expf(e0) - 1.f;
    hs[rr][c0 + 1] = e1 > 0.f ? e1 : __expf(e1) - 1.f;
    hs[rr][c0 + 2] = e2 > 0.f ? e2 : __expf(e2) - 1.f;
    hs[rr][c0 + 3] = e3 > 0.f ? e3 : __expf(e3) - 1.f;
  }
#pragma unroll
  for (int k = 0; k < 4; k++) {
    int lin = t + k * 256;
    wmu_s[lin] = Wmu[lin];
    wlv_s[lin] = Wlv[lin];
  }
#pragma unroll
  for (int k = 0; k < 10; k++) {
    int lin = t + k * 256;
    wd_s[lin] = Wd[lin];
  }
  __syncthreads();
  int r = t >> 4, kk = t & 15;
  float mu = bmu[kk], lv = blv[kk];
#pragma unroll 8
  for (int l = 0; l < 64; l++) {
    float hv = hs[r][l];
    mu += hv * wmu_s[l * 16 + kk];
    lv += hv * wlv_s[l * 16 + kk];
  }
  float z = mu + eps[(size_t)(row0 + r) * CAUS + kk] * __expf(0.5f * lv);
  mu_o[(size_t)(row0 + r) * CAUS + kk] = mu;
  lv_o[(size_t)(row0 + r) * CAUS + kk] = lv;
  zs[r][kk] = z;
  __syncthreads();
#pragma unroll
  for (int p = 0; p < 2; p++) {
    int lin = t + p * 256;
    int rr = lin >> 5, c = lin & 31;
    float acc = bd[c];
#pragma unroll 4
    for (int q = 0; q < 16; q++) acc += zs[rr][q] * wd_s[q * 32 + c];
#pragma unroll 8
    for (int l = 0; l < 64; l++) acc += hs[rr][l] * wd_s[(16 + l) * 32 + c];
    float v = fmaxf(acc, 0.f);
    cs_o[(size_t)(row0 + rr) * CSD + c] = v;
    ie[(size_t)(row0 + rr) * 96 + 64 + c] = v;
  }
}

// ---------------------------------------------------------------------------
// x_recon = sigmoid(cs @ W_dec + b_dec). 32 rows x 128 cols per block.
__global__ __launch_bounds__(256) void k_dec(const float* __restrict__ cs,
                                             const float* __restrict__ Wdec,
                                             const float* __restrict__ bdec,
                                             float* __restrict__ xr) {
  __shared__ float cs_s[32][33];
  __shared__ float4 wd4[32 * 32];
  int t = threadIdx.x;
  int c0 = blockIdx.x * 128;
  int row0 = blockIdx.y * 32;
#pragma unroll
  for (int k = 0; k < 4; k++) {
    int lin = t + k * 256;
    cs_s[lin >> 5][lin & 31] = cs[(size_t)(row0 + (lin >> 5)) * CSD + (lin & 31)];
    int kr = lin >> 5, c4 = lin & 31;
    wd4[lin] = ((const float4*)(Wdec + (size_t)kr * N + c0))[c4];
  }
  __syncthreads();
  int rq = t >> 5, cq = t & 31;
  float4 acc[4];
#pragma unroll
  for (int ri = 0; ri < 4; ri++) acc[ri] = make_float4(0.f, 0.f, 0.f, 0.f);
#pragma unroll 8
  for (int k = 0; k < 32; k++) {
    float4 wv = wd4[k * 32 + cq];
#pragma unroll
    for (int ri = 0; ri < 4; ri++) {
      float cv = cs_s[rq * 4 + ri][k];
      acc[ri].x += cv * wv.x; acc[ri].y += cv * wv.y;
      acc[ri].z += cv * wv.z; acc[ri].w += cv * wv.w;
    }
  }
  float4 bv = ((const float4*)(bdec + c0))[cq];
#pragma unroll
  for (int ri = 0; ri < 4; ri++) {
    float4 v = acc[ri];
    v.x = 1.f / (1.f + __expf(-(v.x + bv.x)));
    v.y = 1.f / (1.f + __expf(-(v.y + bv.y)));
    v.z = 1.f / (1.f + __expf(-(v.z + bv.z)));
    v.w = 1.f / (1.f + __expf(-(v.w + bv.w)));
    ((float4*)(xr + (size_t)(row0 + rq * 4 + ri) * N + c0))[cq] = v;
  }
}

// ---------------------------------------------------------------------------
// t2 = relu(sum_p h1part*dis) @ W2. 4 rows/block.
__global__ __launch_bounds__(256) void k_h1w2(const float* __restrict__ h1src,
                                              int nparts,
                                              const float* __restrict__ dis,
                                              const float* __restrict__ W2,
                                              float* __restrict__ t2) {
  __shared__ float w2s[64 * 64];
  __shared__ float hs[4][65];
  int t = threadIdx.x;
  int row0 = blockIdx.x * 4;
#pragma unroll
  for (int k = 0; k < 16; k++) w2s[t + k * 256] = W2[t + k * 256];
  {
    int rr = t >> 6;
    size_t off = (size_t)row0 * H + t;
    float v = 0.f;
    for (int p = 0; p < nparts; p++) v += h1src[(size_t)p * NH + off];
    hs[rr][t & 63] = fmaxf(v * dis[row0 + rr], 0.f);
  }
  __syncthreads();
  int r = t >> 6, f = t & 63;
  float acc = 0.f;
#pragma unroll 8
  for (int l = 0; l < 64; l++) acc += hs[r][l] * w2s[l * 64 + f];
  t2[(size_t)(row0 + r) * H + f] = acc;
}

// ---------------------------------------------------------------------------
// h2 = relu(sum_p h2part * dis); also writes ie[:, :64].
__global__ __launch_bounds__(256) void k_fin2(const float* __restrict__ h2src,
                                              int nparts,
                                              const float* __restrict__ dis,
                                              float* __restrict__ h2,
                                              float* __restrict__ ie) {
  int idx = blockIdx.x * 256 + threadIdx.x;
  int row = idx >> 6, f = idx & 63;
  float v = 0.f;
  for (int p = 0; p < nparts; p++) v += h2src[(size_t)p * NH + idx];
  v = fmaxf(v * dis[row], 0.f);
  h2[idx] = v;
  ie[(size_t)row * 96 + f] = v;
}

// ---------------------------------------------------------------------------
extern "C" void kernel_launch(void* const* d_in, const int* in_sizes, int n_in,
                              void* d_out, int out_size, void* d_ws, size_t ws_size,
                              hipStream_t stream) {
  const float* x    = (const float*)d_in[0];
  const int*   adj  = (const int*)d_in[1];
  const float* eps  = (const float*)d_in[2];
  const float* Wgat = (const float*)d_in[3];
  const float* agat = (const float*)d_in[4];
  const float* Wmu  = (const float*)d_in[5];
  const float* bmu  = (const float*)d_in[6];
  const float* Wlv  = (const float*)d_in[7];
  const float* blv  = (const float*)d_in[8];
  const float* Wdif = (const float*)d_in[9];
  const float* bdif = (const float*)d_in[10];
  const float* Wdec = (const float*)d_in[11];
  const float* bdec = (const float*)d_in[12];
  const float* Wg1  = (const float*)d_in[13];
  const float* Wg2  = (const float*)d_in[14];

  float* out = (float*)d_out;
  float* xr  = out;                       // (3072,3072)
  float* h2  = out + 9437184;             // (3072,64)
  float* ie  = out + 9633792;             // (3072,96)
  float* cs  = out + 9928704;             // (3072,32)
  float* muo = out + 10027008;            // (3072,16)
  float* lvo = out + 10076160;            // (3072,16)

  // Phase-1 partials live in the xr region of d_out (free until k_dec runs).
  float* xpart = xr;                      // 16*NH = 3,145,728 floats
  float* gpart = xr + 4194304;            // 3,145,728 floats (fits: 7.34M < 9.44M)

  // Workspace layout. Phase-2 partial path needs SLICES*NH in 'part'.
  u64*   packed = (u64*)d_ws;             // 3072*48 u64 = 1.18 MB
  float* wf = (float*)d_ws + 294912;
  bool partial2 = ws_size >= (size_t)(294912 + SLICES * NH + 3 * NH + 5 * N) * 4 + 64;
  size_t part_elems = partial2 ? (size_t)SLICES * NH : (size_t)3 * NH;
  float* part = wf;
  float* h    = part + part_elems;
  float* t1   = h + NH;
  float* t2   = t1 + NH;
  float* sdst = t2 + NH;
  float* ssrc = sdst + N;
  float* mrow = ssrc + N;
  float* zrow = mrow + N;
  float* dis  = zrow + N;

  // ---- adjacency pack + degrees
  k_pack<<<768, 256, 0, stream>>>(adj, packed, dis);
  // ---- GAT: h = x^T @ W_gat (partials into d_out scratch, always)
  k_xt_gemm<1><<<dim3(48, SLICES), 256, 0, stream>>>(x, Wgat, xpart);
  k_reduce_sd<<<768, 256, 0, stream>>>(xpart, SLICES, agat, h, sdst, ssrc);
  k_stats<<<768, 256, 0, stream>>>(packed, sdst, ssrc, mrow, zrow);
  k_gat_av<1><<<dim3(48, SLICES), 256, 0, stream>>>(h, packed, sdst, ssrc, mrow, gpart);
  // ---- VAE + diffusion fusion (reduces + finalizes h_gat on load)
  k_vae<<<192, 256, 0, stream>>>(gpart, SLICES, zrow, eps, Wmu, bmu, Wlv, blv,
                                 Wdif, bdif, muo, lvo, cs, ie);
  // ---- decoder (overwrites xpart/gpart scratch with the real x_recon)
  k_dec<<<dim3(24, 96), 256, 0, stream>>>(cs, Wdec, bdec, xr);
  // ---- GCN stack
  if (partial2) {
    k_xt_gemm<1><<<dim3(48, SLICES), 256, 0, stream>>>(xr, Wg1, part);
    k_reduce<<<192, 256, 0, stream>>>((const float4*)part, SLICES, (float4*)t1);
    k_gcn_agg<1><<<dim3(48, SLICES), 256, 0, stream>>>(t1, packed, dis, part);
    k_h1w2<<<768, 256, 0, stream>>>(part, SLICES, dis, Wg2, t2);
    k_gcn_agg<1><<<dim3(48, SLICES), 256, 0, stream>>>(t2, packed, dis, part);
    k_fin2<<<768, 256, 0, stream>>>(part, SLICES, dis, h2, ie);
  } else {
    float* p0 = part;
    float* p1 = part + NH;
    float* p2 = part + 2 * NH;
    hipMemsetAsync(p0, 0, NH * sizeof(float), stream);
    hipMemsetAsync(p1, 0, NH * sizeof(float), stream);
    hipMemsetAsync(p2, 0, NH * sizeof(float), stream);
    k_xt_gemm<0><<<dim3(48, SLICES), 256, 0, stream>>>(xr, Wg1, p0);
    k_gcn_agg<0><<<dim3(48, SLICES), 256, 0, stream>>>(p0, packed, dis, p1);
    k_h1w2<<<768, 256, 0, stream>>>(p1, 1, dis, Wg2, t2);
    k_gcn_agg<0><<<dim3(48, SLICES), 256, 0, stream>>>(t2, packed, dis, p2);
    k_fin2<<<768, 256, 0, stream>>>(p2, 1, dis, h2, ie);
  }
}

// Round 4
// 177.992 us; speedup vs baseline: 3.2943x; 1.2228x over previous
//
#include <hip/hip_runtime.h>
#include <math.h>

#define N 3072
#define H 64
#define CAUS 16
#define CSD 32
#define GAT_ALPHA 0.35f
#define SLICES 16
#define JSL (N / SLICES)  // 192
#define NH (N * H)        // 196608
typedef unsigned long long u64;
typedef unsigned short u16;
typedef __attribute__((ext_vector_type(4))) float f32x4;
typedef __attribute__((ext_vector_type(8))) short s16x8;
struct alignas(8) u16x4 { u16 x, y, z, w; };

// f32 -> bf16 round-to-nearest-even
__device__ inline u16 f2bf(float f) {
  unsigned u = __builtin_bit_cast(unsigned, f);
  u += 0x7fffu + ((u >> 16) & 1u);
  return (u16)(u >> 16);
}

// ---------------------------------------------------------------------------
// Pack adj row bits into u64 words (bit lane <-> column) + dis = (deg+1)^-1/2.
__global__ __launch_bounds__(256) void k_pack(const int* __restrict__ adj,
                                              u64* __restrict__ packed,
                                              float* __restrict__ dis) {
  int row = blockIdx.x * 4 + (threadIdx.x >> 6);
  int lane = threadIdx.x & 63;
  const int* ar = adj + (size_t)row * N;
  int deg = 0;
  for (int w = 0; w < 48; w++) {
    int v = ar[w * 64 + lane];
    u64 m = __ballot(v > 0);
    if (lane == 0) packed[(size_t)row * 48 + w] = m;
    deg += (v > 0) ? 1 : 0;
  }
  for (int off = 32; off; off >>= 1) deg += __shfl_xor(deg, off);
  if (lane == 0) dis[row] = rsqrtf((float)deg + 1.0f);
}

// ---------------------------------------------------------------------------
// Generic transpose-to-bf16: in f32[R][C] -> out bf16[C][R]. 64x64 tiles.
__global__ __launch_bounds__(256) void k_tbf(const float* __restrict__ in,
                                             u16* __restrict__ outb,
                                             int R, int C) {
  __shared__ float ts[64][68];
  int t = threadIdx.x;
  int r0 = blockIdx.x * 64, c0 = blockIdx.y * 64;
#pragma unroll
  for (int it = 0; it < 4; it++) {
    int r = it * 16 + (t >> 4);
    float4 v = *(const float4*)(in + (size_t)(r0 + r) * C + c0 + (t & 15) * 4);
    ts[r][(t & 15) * 4 + 0] = v.x;
    ts[r][(t & 15) * 4 + 1] = v.y;
    ts[r][(t & 15) * 4 + 2] = v.z;
    ts[r][(t & 15) * 4 + 3] = v.w;
  }
  __syncthreads();
  int c = t >> 2, rch = (t & 3) * 16;
  u16 tmp[16] __attribute__((aligned(16)));
#pragma unroll
  for (int i = 0; i < 16; i++) tmp[i] = f2bf(ts[rch + i][c]);
  u16* orow = outb + (size_t)(c0 + c) * R + r0 + rch;
  *(uint4*)(orow) = *(const uint4*)&tmp[0];
  *(uint4*)(orow + 8) = *(const uint4*)&tmp[8];
}

// ---------------------------------------------------------------------------
// Shared MFMA core: D[64x64] += A_s · B_s^T over K=64 (A_s[m][k], B_s[n][k]).
__device__ inline void mfma_tile(const u16 (&As)[64][72], const u16 (&Bs)[64][72],
                                 f32x4 acc[2][2], int wi, int wf, int il, int kg) {
#pragma unroll
  for (int kk = 0; kk < 64; kk += 32) {
    s16x8 a0 = *(const s16x8*)&As[wi * 32 + il][kk + kg * 8];
    s16x8 a1 = *(const s16x8*)&As[wi * 32 + 16 + il][kk + kg * 8];
    s16x8 b0 = *(const s16x8*)&Bs[wf * 32 + il][kk + kg * 8];
    s16x8 b1 = *(const s16x8*)&Bs[wf * 32 + 16 + il][kk + kg * 8];
    acc[0][0] = __builtin_amdgcn_mfma_f32_16x16x32_bf16(a0, b0, acc[0][0], 0, 0, 0);
    acc[0][1] = __builtin_amdgcn_mfma_f32_16x16x32_bf16(a0, b1, acc[0][1], 0, 0, 0);
    acc[1][0] = __builtin_amdgcn_mfma_f32_16x16x32_bf16(a1, b0, acc[1][0], 0, 0, 0);
    acc[1][1] = __builtin_amdgcn_mfma_f32_16x16x32_bf16(a1, b1, acc[1][1], 0, 0, 0);
  }
}

__device__ inline void store_tile(float* __restrict__ op, int g0, int wi, int wf,
                                  int il, int kg, f32x4 acc[2][2]) {
#pragma unroll
  for (int ti = 0; ti < 2; ti++)
#pragma unroll
    for (int tf = 0; tf < 2; tf++) {
      int col = wf * 32 + tf * 16 + il;
      int rbase = g0 + wi * 32 + ti * 16 + kg * 4;
#pragma unroll
      for (int r = 0; r < 4; r++)
        op[(size_t)(rbase + r) * H + col] = acc[ti][tf][r];
    }
}

// ---------------------------------------------------------------------------
// MFMA GEMM: out[g][f] = sum_{c in slice} A[g][c]*B[f][c], A,B bf16 K-major.
// grid (48 g-tiles, 16 c-slices), 256 thr. Writes f32 partial per slice.
__global__ __launch_bounds__(256) void k_mm(const u16* __restrict__ A,
                                            const u16* __restrict__ B,
                                            float* __restrict__ outp) {
  __shared__ u16 As[64][72];
  __shared__ u16 Bs[64][72];
  int t = threadIdx.x;
  int g0 = blockIdx.x * 64;
  int c0 = blockIdx.y * JSL;
  int w = t >> 6, lane = t & 63, il = lane & 15, kg = lane >> 4;
  int wi = w >> 1, wf = w & 1;
  int sr = t >> 2, sc = t & 3;
  f32x4 z = {0.f, 0.f, 0.f, 0.f};
  f32x4 acc[2][2] = {{z, z}, {z, z}};
  for (int cb = 0; cb < JSL; cb += 64) {
    const uint4* ga = (const uint4*)(A + (size_t)(g0 + sr) * N + c0 + cb) + sc * 2;
    const uint4* gb = (const uint4*)(B + (size_t)sr * N + c0 + cb) + sc * 2;
    uint4 av0 = ga[0], av1 = ga[1];
    uint4 bv0 = gb[0], bv1 = gb[1];
    __syncthreads();
    *(uint4*)&As[sr][sc * 16] = av0;
    *(uint4*)&As[sr][sc * 16 + 8] = av1;
    *(uint4*)&Bs[sr][sc * 16] = bv0;
    *(uint4*)&Bs[sr][sc * 16 + 8] = bv1;
    __syncthreads();
    mfma_tile(As, Bs, acc, wi, wf, il, kg);
  }
  store_tile(outp + (size_t)blockIdx.y * NH, g0, wi, wf, il, kg, acc);
}

// ---------------------------------------------------------------------------
// MFMA masked aggregation. GAT=1: w=exp(leaky(ssrc_i+sdst_j)-m_i) on edges.
// GAT=0: w=(bit+delta_ij)*dis[j].  out[i][f] partial per j-slice.
template <int GAT>
__global__ __launch_bounds__(256) void k_agg(const u16* __restrict__ hT,
                                             const u64* __restrict__ packed,
                                             const float* __restrict__ sdst,
                                             const float* __restrict__ ssrc,
                                             const float* __restrict__ mrow,
                                             const float* __restrict__ dis,
                                             float* __restrict__ outp) {
  __shared__ u16 Ws[64][72];
  __shared__ u16 Hs[64][72];
  __shared__ float ss[64], ms[64];
  int t = threadIdx.x;
  int i0 = blockIdx.x * 64;
  int w = t >> 6, lane = t & 63, il = lane & 15, kg = lane >> 4;
  int wi = w >> 1, wf = w & 1;
  int sr = t >> 2, sc = t & 3;
  if (GAT && t < 64) { ss[t] = ssrc[i0 + t]; ms[t] = mrow[i0 + t]; }
  __syncthreads();
  float sv = GAT ? ss[sr] : 0.f;
  float mv = GAT ? ms[sr] : 0.f;
  f32x4 z = {0.f, 0.f, 0.f, 0.f};
  f32x4 acc[2][2] = {{z, z}, {z, z}};
  int jq = sc * 16;
  for (int jb = 0; jb < JSL; jb += 64) {
    int j0 = blockIdx.y * JSL + jb;
    const uint4* gh = (const uint4*)(hT + (size_t)sr * N + j0) + sc * 2;
    uint4 h0 = gh[0], h1 = gh[1];
    u64 wb = packed[(size_t)(i0 + sr) * 48 + (j0 >> 6)];
    float wv[16];
#pragma unroll
    for (int q = 0; q < 16; q++) {
      int j = j0 + jq + q;
      if (GAT) {
        float e = sv + sdst[j];
        e = e > 0.f ? e : GAT_ALPHA * e;
        wv[q] = ((wb >> (jq + q)) & 1ULL) ? __expf(e - mv) : 0.f;
      } else {
        float cnt = (float)((wb >> (jq + q)) & 1ULL) + ((i0 + sr) == j ? 1.f : 0.f);
        wv[q] = cnt * dis[j];
      }
    }
    __syncthreads();
    *(uint4*)&Hs[sr][sc * 16] = h0;
    *(uint4*)&Hs[sr][sc * 16 + 8] = h1;
#pragma unroll
    for (int q = 0; q < 16; q++) Ws[sr][jq + q] = f2bf(wv[q]);
    __syncthreads();
    mfma_tile(Ws, Hs, acc, wi, wf, il, kg);
  }
  store_tile(outp + (size_t)blockIdx.y * NH, i0, wi, wf, il, kg, acc);
}

// ---------------------------------------------------------------------------
// Reduce nparts partial h buffers -> h f32, fused with s_dst/s_src dots.
__global__ __launch_bounds__(256) void k_reduce_sd(const float* __restrict__ src,
                                                   int nparts,
                                                   const float* __restrict__ a,
                                                   float* __restrict__ h,
                                                   float* __restrict__ sdst,
                                                   float* __restrict__ ssrc) {
  int row = blockIdx.x * 4 + (threadIdx.x >> 6);
  int lane = threadIdx.x & 63;
  size_t off = (size_t)row * H + lane;
  float v = 0.f;
  for (int p = 0; p < nparts; p++) v += src[(size_t)p * NH + off];
  h[off] = v;
  float d1 = v * a[lane];
  float d2 = v * a[H + lane];
  for (int o = 32; o; o >>= 1) {
    d1 += __shfl_xor(d1, o);
    d2 += __shfl_xor(d2, o);
  }
  if (lane == 0) { sdst[row] = d1; ssrc[row] = d2; }
}

// ---------------------------------------------------------------------------
// Generic 16-way float4 partial reduce: dst = sum_p src[p].
__global__ __launch_bounds__(256) void k_reduce(const float4* __restrict__ src,
                                                int nparts,
                                                float4* __restrict__ dst) {
  int idx = blockIdx.x * 256 + threadIdx.x;
  float4 v = {0, 0, 0, 0};
  for (int p = 0; p < nparts; p++) {
    float4 u = src[(size_t)p * (NH / 4) + idx];
    v.x += u.x; v.y += u.y; v.z += u.z; v.w += u.w;
  }
  dst[idx] = v;
}

// ---------------------------------------------------------------------------
// Branchless two-pass softmax stats from packed bits. One wave per row.
__global__ __launch_bounds__(256) void k_stats(const u64* __restrict__ packed,
                                               const float* __restrict__ sdst,
                                               const float* __restrict__ ssrc,
                                               float* __restrict__ mrow,
                                               float* __restrict__ zrow) {
  int row = blockIdx.x * 4 + (threadIdx.x >> 6);
  int lane = threadIdx.x & 63;
  const u64* pr = packed + (size_t)row * 48;
  float si = ssrc[row];
  float M = -INFINITY;
  for (int w = 0; w < 48; w++) {
    u64 wb = pr[w];
    float e = si + sdst[w * 64 + lane];
    e = e > 0.f ? e : GAT_ALPHA * e;
    if ((wb >> lane) & 1ULL) M = fmaxf(M, e);
  }
  for (int off = 32; off; off >>= 1) M = fmaxf(M, __shfl_xor(M, off));
  float S = 0.f;
  for (int w = 0; w < 48; w++) {
    u64 wb = pr[w];
    float e = si + sdst[w * 64 + lane];
    e = e > 0.f ? e : GAT_ALPHA * e;
    if ((wb >> lane) & 1ULL) S += __expf(e - M);
  }
  for (int off = 32; off; off >>= 1) S += __shfl_xor(S, off);
  if (lane == 0) { mrow[row] = M; zrow[row] = fmaxf(S, 1e-30f); }
}

// ---------------------------------------------------------------------------
// VAE + diffusion fusion; sums nparts hacc partials, finalizes elu(./Z) on load.
__global__ __launch_bounds__(256) void k_vae(const float* __restrict__ hacc,
                                             int nparts,
                                             const float* __restrict__ zrow,
                                             const float* __restrict__ eps,
                                             const float* __restrict__ Wmu,
                                             const float* __restrict__ bmu,
                                             const float* __restrict__ Wlv,
                                             const float* __restrict__ blv,
                                             const float* __restrict__ Wd,
                                             const float* __restrict__ bd,
                                             float* __restrict__ mu_o,
                                             float* __restrict__ lv_o,
                                             float* __restrict__ cs_o,
                                             float* __restrict__ ie) {
  __shared__ float hs[16][65];
  __shared__ float zs[16][17];
  __shared__ float wmu_s[64 * 16];
  __shared__ float wlv_s[64 * 16];
  __shared__ float wd_s[80 * 32];
  int t = threadIdx.x;
  int row0 = blockIdx.x * 16;
  {
    const float4* g4 = (const float4*)(hacc + (size_t)row0 * H);
    float4 v = {0, 0, 0, 0};
    for (int p = 0; p < nparts; p++) {
      float4 u = g4[(size_t)p * (NH / 4) + t];
      v.x += u.x; v.y += u.y; v.z += u.z; v.w += u.w;
    }
    int rr = t >> 4, c0 = (t & 15) * 4;
    float zi = 1.0f / zrow[row0 + rr];
    float e0 = v.x * zi, e1 = v.y * zi, e2 = v.z * zi, e3 = v.w * zi;
    hs[rr][c0 + 0] = e0 > 0.f ? e0 : __expf(e0) - 1.f;
    hs[rr][c0 + 1] = e1 > 0.f ? e1 : __expf(e1) - 1.f;
    hs[rr][c0 + 2] = e2 > 0.f ? e2 : __expf(e2) - 1.f;
    hs[rr][c0 + 3] = e3 > 0.f ? e3 : __expf(e3) - 1.f;
  }
#pragma unroll
  for (int k = 0; k < 4; k++) {
    int lin = t + k * 256;
    wmu_s[lin] = Wmu[lin];
    wlv_s[lin] = Wlv[lin];
  }
#pragma unroll
  for (int k = 0; k < 10; k++) {
    int lin = t + k * 256;
    wd_s[lin] = Wd[lin];
  }
  __syncthreads();
  int r = t >> 4, kk = t & 15;
  float mu = bmu[kk], lv = blv[kk];
#pragma unroll 8
  for (int l = 0; l < 64; l++) {
    float hv = hs[r][l];
    mu += hv * wmu_s[l * 16 + kk];
    lv += hv * wlv_s[l * 16 + kk];
  }
  float zc = mu + eps[(size_t)(row0 + r) * CAUS + kk] * __expf(0.5f * lv);
  mu_o[(size_t)(row0 + r) * CAUS + kk] = mu;
  lv_o[(size_t)(row0 + r) * CAUS + kk] = lv;
  zs[r][kk] = zc;
  __syncthreads();
#pragma unroll
  for (int p = 0; p < 2; p++) {
    int lin = t + p * 256;
    int rr = lin >> 5, c = lin & 31;
    float acc = bd[c];
#pragma unroll 4
    for (int q = 0; q < 16; q++) acc += zs[rr][q] * wd_s[q * 32 + c];
#pragma unroll 8
    for (int l = 0; l < 64; l++) acc += hs[rr][l] * wd_s[(16 + l) * 32 + c];
    float v = fmaxf(acc, 0.f);
    cs_o[(size_t)(row0 + rr) * CSD + c] = v;
    ie[(size_t)(row0 + rr) * 96 + 64 + c] = v;
  }
}

// ---------------------------------------------------------------------------
// x_recon = sigmoid(cs @ W_dec + b_dec); also emits xrT bf16 (transposed).
__global__ __launch_bounds__(256) void k_dec(const float* __restrict__ cs,
                                             const float* __restrict__ Wdec,
                                             const float* __restrict__ bdec,
                                             float* __restrict__ xr,
                                             u16* __restrict__ xrT) {
  __shared__ float cs_s[32][33];
  __shared__ float4 wd4[32 * 32];
  int t = threadIdx.x;
  int c0 = blockIdx.x * 128;
  int row0 = blockIdx.y * 32;
#pragma unroll
  for (int k = 0; k < 4; k++) {
    int lin = t + k * 256;
    cs_s[lin >> 5][lin & 31] = cs[(size_t)(row0 + (lin >> 5)) * CSD + (lin & 31)];
    int kr = lin >> 5, c4 = lin & 31;
    wd4[lin] = ((const float4*)(Wdec + (size_t)kr * N + c0))[c4];
  }
  __syncthreads();
  int rq = t >> 5, cq = t & 31;
  float4 acc[4];
#pragma unroll
  for (int ri = 0; ri < 4; ri++) acc[ri] = make_float4(0.f, 0.f, 0.f, 0.f);
#pragma unroll 8
  for (int k = 0; k < 32; k++) {
    float4 wv = wd4[k * 32 + cq];
#pragma unroll
    for (int ri = 0; ri < 4; ri++) {
      float cv = cs_s[rq * 4 + ri][k];
      acc[ri].x += cv * wv.x; acc[ri].y += cv * wv.y;
      acc[ri].z += cv * wv.z; acc[ri].w += cv * wv.w;
    }
  }
  float4 bv = ((const float4*)(bdec + c0))[cq];
  float sv[4][4];
#pragma unroll
  for (int ri = 0; ri < 4; ri++) {
    float4 v = acc[ri];
    sv[ri][0] = 1.f / (1.f + __expf(-(v.x + bv.x)));
    sv[ri][1] = 1.f / (1.f + __expf(-(v.y + bv.y)));
    sv[ri][2] = 1.f / (1.f + __expf(-(v.z + bv.z)));
    sv[ri][3] = 1.f / (1.f + __expf(-(v.w + bv.w)));
    float4 o = make_float4(sv[ri][0], sv[ri][1], sv[ri][2], sv[ri][3]);
    ((float4*)(xr + (size_t)(row0 + rq * 4 + ri) * N + c0))[cq] = o;
  }
#pragma unroll
  for (int cc = 0; cc < 4; cc++) {
    u16x4 tw;
    tw.x = f2bf(sv[0][cc]); tw.y = f2bf(sv[1][cc]);
    tw.z = f2bf(sv[2][cc]); tw.w = f2bf(sv[3][cc]);
    *(u16x4*)(xrT + (size_t)(c0 + cq * 4 + cc) * N + row0 + rq * 4) = tw;
  }
}

// ---------------------------------------------------------------------------
// t2 = relu(sum_p h1part*dis) @ W2. 4 rows/block.
__global__ __launch_bounds__(256) void k_h1w2(const float* __restrict__ h1src,
                                              int nparts,
                                              const float* __restrict__ dis,
                                              const float* __restrict__ W2,
                                              float* __restrict__ t2) {
  __shared__ float w2s[64 * 64];
  __shared__ float hs[4][65];
  int t = threadIdx.x;
  int row0 = blockIdx.x * 4;
#pragma unroll
  for (int k = 0; k < 16; k++) w2s[t + k * 256] = W2[t + k * 256];
  {
    int rr = t >> 6;
    size_t off = (size_t)row0 * H + t;
    float v = 0.f;
    for (int p = 0; p < nparts; p++) v += h1src[(size_t)p * NH + off];
    hs[rr][t & 63] = fmaxf(v * dis[row0 + rr], 0.f);
  }
  __syncthreads();
  int r = t >> 6, f = t & 63;
  float acc = 0.f;
#pragma unroll 8
  for (int l = 0; l < 64; l++) acc += hs[r][l] * w2s[l * 64 + f];
  t2[(size_t)(row0 + r) * H + f] = acc;
}

// ---------------------------------------------------------------------------
// h2 = relu(sum_p h2part * dis); also writes ie[:, :64].
__global__ __launch_bounds__(256) void k_fin2(const float* __restrict__ h2src,
                                              int nparts,
                                              const float* __restrict__ dis,
                                              float* __restrict__ h2,
                                              float* __restrict__ ie) {
  int idx = blockIdx.x * 256 + threadIdx.x;
  int row = idx >> 6, f = idx & 63;
  float v = 0.f;
  for (int p = 0; p < nparts; p++) v += h2src[(size_t)p * NH + idx];
  v = fmaxf(v * dis[row], 0.f);
  h2[idx] = v;
  ie[(size_t)row * 96 + f] = v;
}

// ---------------------------------------------------------------------------
extern "C" void kernel_launch(void* const* d_in, const int* in_sizes, int n_in,
                              void* d_out, int out_size, void* d_ws, size_t ws_size,
                              hipStream_t stream) {
  const float* x    = (const float*)d_in[0];
  const int*   adj  = (const int*)d_in[1];
  const float* eps  = (const float*)d_in[2];
  const float* Wgat = (const float*)d_in[3];
  const float* agat = (const float*)d_in[4];
  const float* Wmu  = (const float*)d_in[5];
  const float* bmu  = (const float*)d_in[6];
  const float* Wlv  = (const float*)d_in[7];
  const float* blv  = (const float*)d_in[8];
  const float* Wdif = (const float*)d_in[9];
  const float* bdif = (const float*)d_in[10];
  const float* Wdec = (const float*)d_in[11];
  const float* bdec = (const float*)d_in[12];
  const float* Wg1  = (const float*)d_in[13];
  const float* Wg2  = (const float*)d_in[14];

  float* out = (float*)d_out;
  float* xr  = out;                       // (3072,3072)
  float* h2  = out + 9437184;             // (3072,64)
  float* ie  = out + 9633792;             // (3072,96)
  float* cs  = out + 9928704;             // (3072,32)
  float* muo = out + 10027008;            // (3072,16)
  float* lvo = out + 10076160;            // (3072,16)

  // Workspace layout (ws_size is 256 MB; total use ~56 MB).
  u64* packed = (u64*)d_ws;               // 3072*48 u64 = 1.18 MB
  u16* us = (u16*)d_ws;
  size_t o = 589824;                      // after packed (in u16 units)
  u16* xT   = us + o; o += (size_t)N * N; // bf16 [g][c] = x^T
  u16* WgT  = us + o; o += NH;            // bf16 [f][c]
  u16* Wg1T = us + o; o += NH;            // bf16 [f][c]
  u16* xrT  = us + o; o += (size_t)N * N; // bf16 [g][c] = xr^T
  u16* hT   = us + o; o += NH;            // bf16 [f][j]
  u16* t1T  = us + o; o += NH;            // bf16 [f][j]
  u16* t2T  = us + o; o += NH;            // bf16 [f][j]
  float* fb   = (float*)(us + o);
  float* part = fb;                       // SLICES*NH f32 partials (reused 5x)
  float* h    = part + (size_t)SLICES * NH;
  float* t1   = h + NH;
  float* t2   = t1 + NH;
  float* sdst = t2 + NH;
  float* ssrc = sdst + N;
  float* mrow = ssrc + N;
  float* zrow = mrow + N;
  float* dis  = zrow + N;

  // ---- prep: adjacency pack + transposed-bf16 operands
  k_pack<<<768, 256, 0, stream>>>(adj, packed, dis);
  k_tbf<<<dim3(48, 48), 256, 0, stream>>>(x, xT, N, N);
  k_tbf<<<dim3(48, 1), 256, 0, stream>>>(Wgat, WgT, N, H);
  k_tbf<<<dim3(48, 1), 256, 0, stream>>>(Wg1, Wg1T, N, H);
  // ---- GAT: h = x^T @ W_gat  (MFMA, 16 K-slices -> f32 partials)
  k_mm<<<dim3(48, SLICES), 256, 0, stream>>>(xT, WgT, part);
  k_reduce_sd<<<768, 256, 0, stream>>>(part, SLICES, agat, h, sdst, ssrc);
  k_tbf<<<dim3(48, 1), 256, 0, stream>>>(h, hT, N, H);
  k_stats<<<768, 256, 0, stream>>>(packed, sdst, ssrc, mrow, zrow);
  k_agg<1><<<dim3(48, SLICES), 256, 0, stream>>>(hT, packed, sdst, ssrc, mrow, dis, part);
  // ---- VAE + diffusion fusion (reduces + finalizes h_gat on load)
  k_vae<<<192, 256, 0, stream>>>(part, SLICES, zrow, eps, Wmu, bmu, Wlv, blv,
                                 Wdif, bdif, muo, lvo, cs, ie);
  // ---- decoder (writes xr f32 + xrT bf16)
  k_dec<<<dim3(24, 96), 256, 0, stream>>>(cs, Wdec, bdec, xr, xrT);
  // ---- GCN stack
  k_mm<<<dim3(48, SLICES), 256, 0, stream>>>(xrT, Wg1T, part);
  k_reduce<<<192, 256, 0, stream>>>((const float4*)part, SLICES, (float4*)t1);
  k_tbf<<<dim3(48, 1), 256, 0, stream>>>(t1, t1T, N, H);
  k_agg<0><<<dim3(48, SLICES), 256, 0, stream>>>(t1T, packed, sdst, ssrc, mrow, dis, part);
  k_h1w2<<<768, 256, 0, stream>>>(part, SLICES, dis, Wg2, t2);
  k_tbf<<<dim3(48, 1), 256, 0, stream>>>(t2, t2T, N, H);
  k_agg<0><<<dim3(48, SLICES), 256, 0, stream>>>(t2T, packed, sdst, ssrc, mrow, dis, part);
  k_fin2<<<768, 256, 0, stream>>>(part, SLICES, dis, h2, ie);
}

// Round 5
// 162.839 us; speedup vs baseline: 3.6008x; 1.0931x over previous
//
#include <hip/hip_runtime.h>
#include <math.h>

#define N 3072
#define H 64
#define CAUS 16
#define CSD 32
#define GAT_ALPHA 0.35f
#define SLICES 16
#define JSL (N / SLICES)  // 192
#define NH (N * H)        // 196608
typedef unsigned long long u64;
typedef unsigned short u16;
typedef __attribute__((ext_vector_type(4))) float f32x4;
typedef __attribute__((ext_vector_type(8))) short s16x8;
struct alignas(8) u16x4 { u16 x, y, z, w; };
struct T4 { float4 r[4]; };

// f32 -> bf16 round-to-nearest-even
__device__ inline u16 f2bf(float f) {
  unsigned u = __builtin_bit_cast(unsigned, f);
  u += 0x7fffu + ((u >> 16) & 1u);
  return (u16)(u >> 16);
}

// ---------------------------------------------------------------------------
// Transpose-staging: src is f32 [k][m] row-major (row stride ld); thread t
// loads a 4k x 4m micro-tile (coalesced float4s)...
__device__ inline T4 t_load(const float* __restrict__ src, int ld, int t) {
  int k4 = (t >> 4) * 4, m4 = (t & 15) * 4;
  T4 o;
#pragma unroll
  for (int d = 0; d < 4; d++)
    o.r[d] = *(const float4*)(src + (size_t)(k4 + d) * ld + m4);
  return o;
}
// ...then writes it transposed+bf16 into LDS dst[m][k] (stride 72).
__device__ inline void t_store(u16 (&dst)[64][72], const T4& v, int t) {
  int k4 = (t >> 4) * 4, m4 = (t & 15) * 4;
  u16x4 c0 = {f2bf(v.r[0].x), f2bf(v.r[1].x), f2bf(v.r[2].x), f2bf(v.r[3].x)};
  u16x4 c1 = {f2bf(v.r[0].y), f2bf(v.r[1].y), f2bf(v.r[2].y), f2bf(v.r[3].y)};
  u16x4 c2 = {f2bf(v.r[0].z), f2bf(v.r[1].z), f2bf(v.r[2].z), f2bf(v.r[3].z)};
  u16x4 c3 = {f2bf(v.r[0].w), f2bf(v.r[1].w), f2bf(v.r[2].w), f2bf(v.r[3].w)};
  *(u16x4*)&dst[m4 + 0][k4] = c0;
  *(u16x4*)&dst[m4 + 1][k4] = c1;
  *(u16x4*)&dst[m4 + 2][k4] = c2;
  *(u16x4*)&dst[m4 + 3][k4] = c3;
}

// ---------------------------------------------------------------------------
// Shared MFMA core: D[64x64] += A_s · B_s^T over K=64 (A_s[m][k], B_s[n][k]).
__device__ inline void mfma_tile(const u16 (&As)[64][72], const u16 (&Bs)[64][72],
                                 f32x4 acc[2][2], int wi, int wf, int il, int kg) {
#pragma unroll
  for (int kk = 0; kk < 64; kk += 32) {
    s16x8 a0 = *(const s16x8*)&As[wi * 32 + il][kk + kg * 8];
    s16x8 a1 = *(const s16x8*)&As[wi * 32 + 16 + il][kk + kg * 8];
    s16x8 b0 = *(const s16x8*)&Bs[wf * 32 + il][kk + kg * 8];
    s16x8 b1 = *(const s16x8*)&Bs[wf * 32 + 16 + il][kk + kg * 8];
    acc[0][0] = __builtin_amdgcn_mfma_f32_16x16x32_bf16(a0, b0, acc[0][0], 0, 0, 0);
    acc[0][1] = __builtin_amdgcn_mfma_f32_16x16x32_bf16(a0, b1, acc[0][1], 0, 0, 0);
    acc[1][0] = __builtin_amdgcn_mfma_f32_16x16x32_bf16(a1, b0, acc[1][0], 0, 0, 0);
    acc[1][1] = __builtin_amdgcn_mfma_f32_16x16x32_bf16(a1, b1, acc[1][1], 0, 0, 0);
  }
}

__device__ inline void store_tile(float* __restrict__ op, int g0, int wi, int wf,
                                  int il, int kg, f32x4 acc[2][2]) {
#pragma unroll
  for (int ti = 0; ti < 2; ti++)
#pragma unroll
    for (int tf = 0; tf < 2; tf++) {
      int col = wf * 32 + tf * 16 + il;
      int rbase = g0 + wi * 32 + ti * 16 + kg * 4;
#pragma unroll
      for (int r = 0; r < 4; r++)
        op[(size_t)(rbase + r) * H + col] = acc[ti][tf][r];
    }
}

// ---------------------------------------------------------------------------
// Pack adj row bits into u64 words (bit lane <-> column) + dis = (deg+1)^-1/2.
__global__ __launch_bounds__(256) void k_pack(const int* __restrict__ adj,
                                              u64* __restrict__ packed,
                                              float* __restrict__ dis) {
  int row = blockIdx.x * 4 + (threadIdx.x >> 6);
  int lane = threadIdx.x & 63;
  const int* ar = adj + (size_t)row * N;
  int deg = 0;
  for (int w = 0; w < 48; w++) {
    int v = ar[w * 64 + lane];
    u64 m = __ballot(v > 0);
    if (lane == 0) packed[(size_t)row * 48 + w] = m;
    deg += (v > 0) ? 1 : 0;
  }
  for (int off = 32; off; off >>= 1) deg += __shfl_xor(deg, off);
  if (lane == 0) dis[row] = rsqrtf((float)deg + 1.0f);
}

// ---------------------------------------------------------------------------
// MFMA GEMM with in-kernel transpose staging:
// out[m][n] = sum_{k in slice} A[k][m] * B[k][n];  A: f32 stride lda, B: stride ldb.
__global__ __launch_bounds__(256) void k_mm(const float* __restrict__ A, int lda,
                                            const float* __restrict__ B, int ldb,
                                            float* __restrict__ outp) {
  __shared__ u16 As[64][72];
  __shared__ u16 Bs[64][72];
  int t = threadIdx.x;
  int g0 = blockIdx.x * 64;
  int c0 = blockIdx.y * JSL;
  int w = t >> 6, lane = t & 63, il = lane & 15, kg = lane >> 4;
  int wi = w >> 1, wf = w & 1;
  f32x4 z = {0.f, 0.f, 0.f, 0.f};
  f32x4 acc[2][2] = {{z, z}, {z, z}};
  for (int cb = 0; cb < JSL; cb += 64) {
    T4 av = t_load(A + (size_t)(c0 + cb) * lda + g0, lda, t);
    T4 bv = t_load(B + (size_t)(c0 + cb) * ldb, ldb, t);
    __syncthreads();
    t_store(As, av, t);
    t_store(Bs, bv, t);
    __syncthreads();
    mfma_tile(As, Bs, acc, wi, wf, il, kg);
  }
  store_tile(outp + (size_t)blockIdx.y * NH, g0, wi, wf, il, kg, acc);
}

// ---------------------------------------------------------------------------
// MFMA masked aggregation. GAT=1: w=exp(leaky(ssrc_i+sdst_j)-m_i) on edges.
// GAT=0: w=(bit+delta_ij)*dis[j]. Reads hin f32 [j][f] directly (staged).
template <int GAT>
__global__ __launch_bounds__(256) void k_agg(const float* __restrict__ hin,
                                             const u64* __restrict__ packed,
                                             const float* __restrict__ sdst,
                                             const float* __restrict__ ssrc,
                                             const float* __restrict__ mrow,
                                             const float* __restrict__ dis,
                                             float* __restrict__ outp) {
  __shared__ u16 Ws[64][72];
  __shared__ u16 Hs[64][72];
  __shared__ float ss[64], ms[64];
  int t = threadIdx.x;
  int i0 = blockIdx.x * 64;
  int w = t >> 6, lane = t & 63, il = lane & 15, kg = lane >> 4;
  int wi = w >> 1, wf = w & 1;
  int sr = t >> 2, jq = (t & 3) * 16;
  if (GAT && t < 64) { ss[t] = ssrc[i0 + t]; ms[t] = mrow[i0 + t]; }
  __syncthreads();
  float sv = GAT ? ss[sr] : 0.f;
  float mv = GAT ? ms[sr] : 0.f;
  f32x4 z = {0.f, 0.f, 0.f, 0.f};
  f32x4 acc[2][2] = {{z, z}, {z, z}};
  for (int jb = 0; jb < JSL; jb += 64) {
    int j0 = blockIdx.y * JSL + jb;
    T4 hv = t_load(hin + (size_t)j0 * H, H, t);
    u64 wb = packed[(size_t)(i0 + sr) * 48 + (j0 >> 6)];
    float wv[16];
    if (GAT) {
      const float4* sd4 = (const float4*)(sdst + j0 + jq);
      float4 s0 = sd4[0], s1 = sd4[1], s2 = sd4[2], s3 = sd4[3];
#define PR(val, q) { float e = sv + (val); e = e > 0.f ? e : GAT_ALPHA * e; \
  wv[q] = ((wb >> (jq + (q))) & 1ULL) ? __expf(e - mv) : 0.f; }
      PR(s0.x, 0) PR(s0.y, 1) PR(s0.z, 2) PR(s0.w, 3)
      PR(s1.x, 4) PR(s1.y, 5) PR(s1.z, 6) PR(s1.w, 7)
      PR(s2.x, 8) PR(s2.y, 9) PR(s2.z, 10) PR(s2.w, 11)
      PR(s3.x, 12) PR(s3.y, 13) PR(s3.z, 14) PR(s3.w, 15)
#undef PR
    } else {
      const float4* dd4 = (const float4*)(dis + j0 + jq);
      float4 d0 = dd4[0], d1 = dd4[1], d2 = dd4[2], d3 = dd4[3];
#define PRG(val, q) { float cnt = (float)((wb >> (jq + (q))) & 1ULL) + \
  ((i0 + sr) == (j0 + jq + (q)) ? 1.f : 0.f); wv[q] = cnt * (val); }
      PRG(d0.x, 0) PRG(d0.y, 1) PRG(d0.z, 2) PRG(d0.w, 3)
      PRG(d1.x, 4) PRG(d1.y, 5) PRG(d1.z, 6) PRG(d1.w, 7)
      PRG(d2.x, 8) PRG(d2.y, 9) PRG(d2.z, 10) PRG(d2.w, 11)
      PRG(d3.x, 12) PRG(d3.y, 13) PRG(d3.z, 14) PRG(d3.w, 15)
#undef PRG
    }
    __syncthreads();
    t_store(Hs, hv, t);
#pragma unroll
    for (int q = 0; q < 16; q++) Ws[sr][jq + q] = f2bf(wv[q]);
    __syncthreads();
    mfma_tile(Ws, Hs, acc, wi, wf, il, kg);
  }
  store_tile(outp + (size_t)blockIdx.y * NH, i0, wi, wf, il, kg, acc);
}

// ---------------------------------------------------------------------------
// Reduce nparts partial h buffers -> h f32, fused with s_dst/s_src dots.
__global__ __launch_bounds__(256) void k_reduce_sd(const float* __restrict__ src,
                                                   int nparts,
                                                   const float* __restrict__ a,
                                                   float* __restrict__ h,
                                                   float* __restrict__ sdst,
                                                   float* __restrict__ ssrc) {
  int row = blockIdx.x * 4 + (threadIdx.x >> 6);
  int lane = threadIdx.x & 63;
  size_t off = (size_t)row * H + lane;
  float v = 0.f;
  for (int p = 0; p < nparts; p++) v += src[(size_t)p * NH + off];
  h[off] = v;
  float d1 = v * a[lane];
  float d2 = v * a[H + lane];
  for (int o = 32; o; o >>= 1) {
    d1 += __shfl_xor(d1, o);
    d2 += __shfl_xor(d2, o);
  }
  if (lane == 0) { sdst[row] = d1; ssrc[row] = d2; }
}

// ---------------------------------------------------------------------------
// Generic 16-way float4 partial reduce: dst = sum_p src[p].
__global__ __launch_bounds__(256) void k_reduce(const float4* __restrict__ src,
                                                int nparts,
                                                float4* __restrict__ dst) {
  int idx = blockIdx.x * 256 + threadIdx.x;
  float4 v = {0, 0, 0, 0};
  for (int p = 0; p < nparts; p++) {
    float4 u = src[(size_t)p * (NH / 4) + idx];
    v.x += u.x; v.y += u.y; v.z += u.z; v.w += u.w;
  }
  dst[idx] = v;
}

// ---------------------------------------------------------------------------
// Branchless two-pass softmax stats from packed bits. One wave per row.
__global__ __launch_bounds__(256) void k_stats(const u64* __restrict__ packed,
                                               const float* __restrict__ sdst,
                                               const float* __restrict__ ssrc,
                                               float* __restrict__ mrow,
                                               float* __restrict__ zrow) {
  int row = blockIdx.x * 4 + (threadIdx.x >> 6);
  int lane = threadIdx.x & 63;
  const u64* pr = packed + (size_t)row * 48;
  float si = ssrc[row];
  float M = -INFINITY;
  for (int w = 0; w < 48; w++) {
    u64 wb = pr[w];
    float e = si + sdst[w * 64 + lane];
    e = e > 0.f ? e : GAT_ALPHA * e;
    if ((wb >> lane) & 1ULL) M = fmaxf(M, e);
  }
  for (int off = 32; off; off >>= 1) M = fmaxf(M, __shfl_xor(M, off));
  float S = 0.f;
  for (int w = 0; w < 48; w++) {
    u64 wb = pr[w];
    float e = si + sdst[w * 64 + lane];
    e = e > 0.f ? e : GAT_ALPHA * e;
    if ((wb >> lane) & 1ULL) S += __expf(e - M);
  }
  for (int off = 32; off; off >>= 1) S += __shfl_xor(S, off);
  if (lane == 0) { mrow[row] = M; zrow[row] = fmaxf(S, 1e-30f); }
}

// ---------------------------------------------------------------------------
// VAE + diffusion fusion; sums nparts hacc partials, finalizes elu(./Z) on load.
__global__ __launch_bounds__(256) void k_vae(const float* __restrict__ hacc,
                                             int nparts,
                                             const float* __restrict__ zrow,
                                             const float* __restrict__ eps,
                                             const float* __restrict__ Wmu,
                                             const float* __restrict__ bmu,
                                             const float* __restrict__ Wlv,
                                             const float* __restrict__ blv,
                                             const float* __restrict__ Wd,
                                             const float* __restrict__ bd,
                                             float* __restrict__ mu_o,
                                             float* __restrict__ lv_o,
                                             float* __restrict__ cs_o,
                                             float* __restrict__ ie) {
  __shared__ float hs[16][65];
  __shared__ float zs[16][17];
  __shared__ float wmu_s[64 * 16];
  __shared__ float wlv_s[64 * 16];
  __shared__ float wd_s[80 * 32];
  int t = threadIdx.x;
  int row0 = blockIdx.x * 16;
  {
    const float4* g4 = (const float4*)(hacc + (size_t)row0 * H);
    float4 v = {0, 0, 0, 0};
    for (int p = 0; p < nparts; p++) {
      float4 u = g4[(size_t)p * (NH / 4) + t];
      v.x += u.x; v.y += u.y; v.z += u.z; v.w += u.w;
    }
    int rr = t >> 4, c0 = (t & 15) * 4;
    float zi = 1.0f / zrow[row0 + rr];
    float e0 = v.x * zi, e1 = v.y * zi, e2 = v.z * zi, e3 = v.w * zi;
    hs[rr][c0 + 0] = e0 > 0.f ? e0 : __expf(e0) - 1.f;
    hs[rr][c0 + 1] = e1 > 0.f ? e1 : __expf(e1) - 1.f;
    hs[rr][c0 + 2] = e2 > 0.f ? e2 : __expf(e2) - 1.f;
    hs[rr][c0 + 3] = e3 > 0.f ? e3 : __expf(e3) - 1.f;
  }
#pragma unroll
  for (int k = 0; k < 4; k++) {
    int lin = t + k * 256;
    wmu_s[lin] = Wmu[lin];
    wlv_s[lin] = Wlv[lin];
  }
#pragma unroll
  for (int k = 0; k < 10; k++) {
    int lin = t + k * 256;
    wd_s[lin] = Wd[lin];
  }
  __syncthreads();
  int r = t >> 4, kk = t & 15;
  float mu = bmu[kk], lv = blv[kk];
#pragma unroll 8
  for (int l = 0; l < 64; l++) {
    float hv = hs[r][l];
    mu += hv * wmu_s[l * 16 + kk];
    lv += hv * wlv_s[l * 16 + kk];
  }
  float zc = mu + eps[(size_t)(row0 + r) * CAUS + kk] * __expf(0.5f * lv);
  mu_o[(size_t)(row0 + r) * CAUS + kk] = mu;
  lv_o[(size_t)(row0 + r) * CAUS + kk] = lv;
  zs[r][kk] = zc;
  __syncthreads();
#pragma unroll
  for (int p = 0; p < 2; p++) {
    int lin = t + p * 256;
    int rr = lin >> 5, c = lin & 31;
    float acc = bd[c];
#pragma unroll 4
    for (int q = 0; q < 16; q++) acc += zs[rr][q] * wd_s[q * 32 + c];
#pragma unroll 8
    for (int l = 0; l < 64; l++) acc += hs[rr][l] * wd_s[(16 + l) * 32 + c];
    float v = fmaxf(acc, 0.f);
    cs_o[(size_t)(row0 + rr) * CSD + c] = v;
    ie[(size_t)(row0 + rr) * 96 + 64 + c] = v;
  }
}

// ---------------------------------------------------------------------------
// x_recon = sigmoid(cs @ W_dec + b_dec). 32 rows x 128 cols per block.
__global__ __launch_bounds__(256) void k_dec(const float* __restrict__ cs,
                                             const float* __restrict__ Wdec,
                                             const float* __restrict__ bdec,
                                             float* __restrict__ xr) {
  __shared__ float cs_s[32][33];
  __shared__ float4 wd4[32 * 32];
  int t = threadIdx.x;
  int c0 = blockIdx.x * 128;
  int row0 = blockIdx.y * 32;
#pragma unroll
  for (int k = 0; k < 4; k++) {
    int lin = t + k * 256;
    cs_s[lin >> 5][lin & 31] = cs[(size_t)(row0 + (lin >> 5)) * CSD + (lin & 31)];
    int kr = lin >> 5, c4 = lin & 31;
    wd4[lin] = ((const float4*)(Wdec + (size_t)kr * N + c0))[c4];
  }
  __syncthreads();
  int rq = t >> 5, cq = t & 31;
  float4 acc[4];
#pragma unroll
  for (int ri = 0; ri < 4; ri++) acc[ri] = make_float4(0.f, 0.f, 0.f, 0.f);
#pragma unroll 8
  for (int k = 0; k < 32; k++) {
    float4 wv = wd4[k * 32 + cq];
#pragma unroll
    for (int ri = 0; ri < 4; ri++) {
      float cv = cs_s[rq * 4 + ri][k];
      acc[ri].x += cv * wv.x; acc[ri].y += cv * wv.y;
      acc[ri].z += cv * wv.z; acc[ri].w += cv * wv.w;
    }
  }
  float4 bv = ((const float4*)(bdec + c0))[cq];
#pragma unroll
  for (int ri = 0; ri < 4; ri++) {
    float4 v = acc[ri];
    v.x = 1.f / (1.f + __expf(-(v.x + bv.x)));
    v.y = 1.f / (1.f + __expf(-(v.y + bv.y)));
    v.z = 1.f / (1.f + __expf(-(v.z + bv.z)));
    v.w = 1.f / (1.f + __expf(-(v.w + bv.w)));
    ((float4*)(xr + (size_t)(row0 + rq * 4 + ri) * N + c0))[cq] = v;
  }
}

// ---------------------------------------------------------------------------
// t2 = relu(sum_p h1part*dis) @ W2. 4 rows/block.
__global__ __launch_bounds__(256) void k_h1w2(const float* __restrict__ h1src,
                                              int nparts,
                                              const float* __restrict__ dis,
                                              const float* __restrict__ W2,
                                              float* __restrict__ t2) {
  __shared__ float w2s[64 * 64];
  __shared__ float hs[4][65];
  int t = threadIdx.x;
  int row0 = blockIdx.x * 4;
#pragma unroll
  for (int k = 0; k < 16; k++) w2s[t + k * 256] = W2[t + k * 256];
  {
    int rr = t >> 6;
    size_t off = (size_t)row0 * H + t;
    float v = 0.f;
    for (int p = 0; p < nparts; p++) v += h1src[(size_t)p * NH + off];
    hs[rr][t & 63] = fmaxf(v * dis[row0 + rr], 0.f);
  }
  __syncthreads();
  int r = t >> 6, f = t & 63;
  float acc = 0.f;
#pragma unroll 8
  for (int l = 0; l < 64; l++) acc += hs[r][l] * w2s[l * 64 + f];
  t2[(size_t)(row0 + r) * H + f] = acc;
}

// ---------------------------------------------------------------------------
// h2 = relu(sum_p h2part * dis); also writes ie[:, :64].
__global__ __launch_bounds__(256) void k_fin2(const float* __restrict__ h2src,
                                              int nparts,
                                              const float* __restrict__ dis,
                                              float* __restrict__ h2,
                                              float* __restrict__ ie) {
  int idx = blockIdx.x * 256 + threadIdx.x;
  int row = idx >> 6, f = idx & 63;
  float v = 0.f;
  for (int p = 0; p < nparts; p++) v += h2src[(size_t)p * NH + idx];
  v = fmaxf(v * dis[row], 0.f);
  h2[idx] = v;
  ie[(size_t)row * 96 + f] = v;
}

// ---------------------------------------------------------------------------
extern "C" void kernel_launch(void* const* d_in, const int* in_sizes, int n_in,
                              void* d_out, int out_size, void* d_ws, size_t ws_size,
                              hipStream_t stream) {
  const float* x    = (const float*)d_in[0];
  const int*   adj  = (const int*)d_in[1];
  const float* eps  = (const float*)d_in[2];
  const float* Wgat = (const float*)d_in[3];
  const float* agat = (const float*)d_in[4];
  const float* Wmu  = (const float*)d_in[5];
  const float* bmu  = (const float*)d_in[6];
  const float* Wlv  = (const float*)d_in[7];
  const float* blv  = (const float*)d_in[8];
  const float* Wdif = (const float*)d_in[9];
  const float* bdif = (const float*)d_in[10];
  const float* Wdec = (const float*)d_in[11];
  const float* bdec = (const float*)d_in[12];
  const float* Wg1  = (const float*)d_in[13];
  const float* Wg2  = (const float*)d_in[14];

  float* out = (float*)d_out;
  float* xr  = out;                       // (3072,3072)
  float* h2  = out + 9437184;             // (3072,64)
  float* ie  = out + 9633792;             // (3072,96)
  float* cs  = out + 9928704;             // (3072,32)
  float* muo = out + 10027008;            // (3072,16)
  float* lvo = out + 10076160;            // (3072,16)

  // Workspace (~17 MB of 256 MB)
  u64* packed = (u64*)d_ws;               // 3072*48 u64 = 1.18 MB
  float* wf   = (float*)d_ws + 294912;
  float* part = wf;                       // SLICES*NH f32 partials (reused 5x)
  float* h    = part + (size_t)SLICES * NH;
  float* t1   = h + NH;
  float* t2   = t1 + NH;
  float* sdst = t2 + NH;
  float* ssrc = sdst + N;
  float* mrow = ssrc + N;
  float* zrow = mrow + N;
  float* dis  = zrow + N;

  // ---- adjacency pack + degrees
  k_pack<<<768, 256, 0, stream>>>(adj, packed, dis);
  // ---- GAT: h = x^T @ W_gat  (in-kernel transpose staging, f32 partials)
  k_mm<<<dim3(48, SLICES), 256, 0, stream>>>(x, N, Wgat, H, part);
  k_reduce_sd<<<768, 256, 0, stream>>>(part, SLICES, agat, h, sdst, ssrc);
  k_stats<<<768, 256, 0, stream>>>(packed, sdst, ssrc, mrow, zrow);
  k_agg<1><<<dim3(48, SLICES), 256, 0, stream>>>(h, packed, sdst, ssrc, mrow, dis, part);
  // ---- VAE + diffusion fusion (reduces + finalizes h_gat on load)
  k_vae<<<192, 256, 0, stream>>>(part, SLICES, zrow, eps, Wmu, bmu, Wlv, blv,
                                 Wdif, bdif, muo, lvo, cs, ie);
  // ---- decoder
  k_dec<<<dim3(24, 96), 256, 0, stream>>>(cs, Wdec, bdec, xr);
  // ---- GCN stack
  k_mm<<<dim3(48, SLICES), 256, 0, stream>>>(xr, N, Wg1, H, part);
  k_reduce<<<192, 256, 0, stream>>>((const float4*)part, SLICES, (float4*)t1);
  k_agg<0><<<dim3(48, SLICES), 256, 0, stream>>>(t1, packed, sdst, ssrc, mrow, dis, part);
  k_h1w2<<<768, 256, 0, stream>>>(part, SLICES, dis, Wg2, t2);
  k_agg<0><<<dim3(48, SLICES), 256, 0, stream>>>(t2, packed, sdst, ssrc, mrow, dis, part);
  k_fin2<<<768, 256, 0, stream>>>(part, SLICES, dis, h2, ie);
}

// Round 6
// 126.336 us; speedup vs baseline: 4.6412x; 1.2889x over previous
//
#include <hip/hip_runtime.h>
#include <math.h>

#define N 3072
#define H 64
#define CAUS 16
#define CSD 32
#define GAT_ALPHA 0.35f
#define SLICES 16
#define JSL (N / SLICES)  // 192
#define NH (N * H)        // 196608
typedef unsigned long long u64;
typedef unsigned short u16;
typedef __attribute__((ext_vector_type(4))) float f32x4;
typedef __attribute__((ext_vector_type(8))) short s16x8;
struct alignas(8) u16x4 { u16 x, y, z, w; };
struct T4 { float4 r[4]; };

// f32 -> bf16 round-to-nearest-even
__device__ inline u16 f2bf(float f) {
  unsigned u = __builtin_bit_cast(unsigned, f);
  u += 0x7fffu + ((u >> 16) & 1u);
  return (u16)(u >> 16);
}

// ---------------------------------------------------------------------------
// Transpose-staging: src is f32 [k][m] row-major (row stride ld); thread t
// loads a 4k x 4m micro-tile (coalesced float4s)...
__device__ inline T4 t_load(const float* __restrict__ src, int ld, int t) {
  int k4 = (t >> 4) * 4, m4 = (t & 15) * 4;
  T4 o;
#pragma unroll
  for (int d = 0; d < 4; d++)
    o.r[d] = *(const float4*)(src + (size_t)(k4 + d) * ld + m4);
  return o;
}
// ...then writes it transposed+bf16 into LDS dst[m][k] (stride 72).
__device__ inline void t_store(u16 (&dst)[64][72], const T4& v, int t) {
  int k4 = (t >> 4) * 4, m4 = (t & 15) * 4;
  u16x4 c0 = {f2bf(v.r[0].x), f2bf(v.r[1].x), f2bf(v.r[2].x), f2bf(v.r[3].x)};
  u16x4 c1 = {f2bf(v.r[0].y), f2bf(v.r[1].y), f2bf(v.r[2].y), f2bf(v.r[3].y)};
  u16x4 c2 = {f2bf(v.r[0].z), f2bf(v.r[1].z), f2bf(v.r[2].z), f2bf(v.r[3].z)};
  u16x4 c3 = {f2bf(v.r[0].w), f2bf(v.r[1].w), f2bf(v.r[2].w), f2bf(v.r[3].w)};
  *(u16x4*)&dst[m4 + 0][k4] = c0;
  *(u16x4*)&dst[m4 + 1][k4] = c1;
  *(u16x4*)&dst[m4 + 2][k4] = c2;
  *(u16x4*)&dst[m4 + 3][k4] = c3;
}

// ---------------------------------------------------------------------------
// Shared MFMA core: D[64x64] += A_s · B_s^T over K=64 (A_s[m][k], B_s[n][k]).
__device__ inline void mfma_tile(const u16 (&As)[64][72], const u16 (&Bs)[64][72],
                                 f32x4 acc[2][2], int wi, int wf, int il, int kg) {
#pragma unroll
  for (int kk = 0; kk < 64; kk += 32) {
    s16x8 a0 = *(const s16x8*)&As[wi * 32 + il][kk + kg * 8];
    s16x8 a1 = *(const s16x8*)&As[wi * 32 + 16 + il][kk + kg * 8];
    s16x8 b0 = *(const s16x8*)&Bs[wf * 32 + il][kk + kg * 8];
    s16x8 b1 = *(const s16x8*)&Bs[wf * 32 + 16 + il][kk + kg * 8];
    acc[0][0] = __builtin_amdgcn_mfma_f32_16x16x32_bf16(a0, b0, acc[0][0], 0, 0, 0);
    acc[0][1] = __builtin_amdgcn_mfma_f32_16x16x32_bf16(a0, b1, acc[0][1], 0, 0, 0);
    acc[1][0] = __builtin_amdgcn_mfma_f32_16x16x32_bf16(a1, b0, acc[1][0], 0, 0, 0);
    acc[1][1] = __builtin_amdgcn_mfma_f32_16x16x32_bf16(a1, b1, acc[1][1], 0, 0, 0);
  }
}

__device__ inline void store_tile(float* __restrict__ op, int g0, int wi, int wf,
                                  int il, int kg, f32x4 acc[2][2]) {
#pragma unroll
  for (int ti = 0; ti < 2; ti++)
#pragma unroll
    for (int tf = 0; tf < 2; tf++) {
      int col = wf * 32 + tf * 16 + il;
      int rbase = g0 + wi * 32 + ti * 16 + kg * 4;
#pragma unroll
      for (int r = 0; r < 4; r++)
        op[(size_t)(rbase + r) * H + col] = acc[ti][tf][r];
    }
}

// ---------------------------------------------------------------------------
// Pack adj row bits into u64 words (bit lane <-> column) + dis = (deg+1)^-1/2.
__global__ __launch_bounds__(256) void k_pack(const int* __restrict__ adj,
                                              u64* __restrict__ packed,
                                              float* __restrict__ dis) {
  int row = blockIdx.x * 4 + (threadIdx.x >> 6);
  int lane = threadIdx.x & 63;
  const int* ar = adj + (size_t)row * N;
  int deg = 0;
  for (int w = 0; w < 48; w++) {
    int v = ar[w * 64 + lane];
    u64 m = __ballot(v > 0);
    if (lane == 0) packed[(size_t)row * 48 + w] = m;
    deg += (v > 0) ? 1 : 0;
  }
  for (int off = 32; off; off >>= 1) deg += __shfl_xor(deg, off);
  if (lane == 0) dis[row] = rsqrtf((float)deg + 1.0f);
}

// ---------------------------------------------------------------------------
// MFMA GEMM, staged transpose, software-pipelined loads:
// out[m][n] = sum_{k in slice} A[k][m] * B[k][n].
__global__ __launch_bounds__(256) void k_mm(const float* __restrict__ A, int lda,
                                            const float* __restrict__ B, int ldb,
                                            float* __restrict__ outp) {
  __shared__ u16 As[64][72];
  __shared__ u16 Bs[64][72];
  int t = threadIdx.x;
  int g0 = blockIdx.x * 64;
  int c0 = blockIdx.y * JSL;
  int w = t >> 6, lane = t & 63, il = lane & 15, kg = lane >> 4;
  int wi = w >> 1, wf = w & 1;
  f32x4 z = {0.f, 0.f, 0.f, 0.f};
  f32x4 acc[2][2] = {{z, z}, {z, z}};
  T4 av = t_load(A + (size_t)c0 * lda + g0, lda, t);
  T4 bv = t_load(B + (size_t)c0 * ldb, ldb, t);
  for (int cb = 0; cb < JSL; cb += 64) {
    __syncthreads();
    t_store(As, av, t);
    t_store(Bs, bv, t);
    if (cb + 64 < JSL) {
      av = t_load(A + (size_t)(c0 + cb + 64) * lda + g0, lda, t);
      bv = t_load(B + (size_t)(c0 + cb + 64) * ldb, ldb, t);
    }
    __syncthreads();
    mfma_tile(As, Bs, acc, wi, wf, il, kg);
  }
  store_tile(outp + (size_t)blockIdx.y * NH, g0, wi, wf, il, kg, acc);
}

// ---------------------------------------------------------------------------
// Weight generators for k_agg (unshifted exp for GAT; normalized adj for GCN).
__device__ inline void gat_w(float sv, const float* __restrict__ sdst, u64 wb,
                             int j0, int jq, float (&wv)[16], float& zacc) {
  const float4* sd4 = (const float4*)(sdst + j0 + jq);
  float4 s0 = sd4[0], s1 = sd4[1], s2 = sd4[2], s3 = sd4[3];
  float sf[16] = {s0.x, s0.y, s0.z, s0.w, s1.x, s1.y, s1.z, s1.w,
                  s2.x, s2.y, s2.z, s2.w, s3.x, s3.y, s3.z, s3.w};
#pragma unroll
  for (int q = 0; q < 16; q++) {
    float e = sv + sf[q];
    e = e > 0.f ? e : GAT_ALPHA * e;
    float ww = ((wb >> (jq + q)) & 1ULL) ? __expf(e) : 0.f;
    wv[q] = ww;
    zacc += ww;
  }
}
__device__ inline void gcn_w(const float* __restrict__ dis, u64 wb, int i,
                             int j0, int jq, float (&wv)[16]) {
  const float4* dd4 = (const float4*)(dis + j0 + jq);
  float4 d0 = dd4[0], d1 = dd4[1], d2 = dd4[2], d3 = dd4[3];
  float df[16] = {d0.x, d0.y, d0.z, d0.w, d1.x, d1.y, d1.z, d1.w,
                  d2.x, d2.y, d2.z, d2.w, d3.x, d3.y, d3.z, d3.w};
#pragma unroll
  for (int q = 0; q < 16; q++) {
    float cnt = (float)((wb >> (jq + q)) & 1ULL) + (i == (j0 + jq + q) ? 1.f : 0.f);
    wv[q] = cnt * df[q];
  }
}

// ---------------------------------------------------------------------------
// MFMA masked aggregation, pipelined. GAT=1: w=exp(leaky(ssrc_i+sdst_j)) on
// edges (UNSHIFTED; Z row-sums emitted to zpart). GAT=0: w=(bit+delta)*dis[j].
template <int GAT>
__global__ __launch_bounds__(256) void k_agg(const float* __restrict__ hin,
                                             const u64* __restrict__ packed,
                                             const float* __restrict__ sdst,
                                             const float* __restrict__ ssrc,
                                             const float* __restrict__ dis,
                                             float* __restrict__ outp,
                                             float* __restrict__ zpart) {
  __shared__ u16 Ws[64][72];
  __shared__ u16 Hs[64][72];
  __shared__ float ss[64];
  int t = threadIdx.x;
  int i0 = blockIdx.x * 64;
  int w = t >> 6, lane = t & 63, il = lane & 15, kg = lane >> 4;
  int wi = w >> 1, wf = w & 1;
  int sr = t >> 2, jq = (t & 3) * 16;
  if (GAT && t < 64) ss[t] = ssrc[i0 + t];
  __syncthreads();
  float sv = GAT ? ss[sr] : 0.f;
  float zacc = 0.f;
  f32x4 z = {0.f, 0.f, 0.f, 0.f};
  f32x4 acc[2][2] = {{z, z}, {z, z}};
  int jbase = blockIdx.y * JSL;
  T4 hv = t_load(hin + (size_t)jbase * H, H, t);
  float wv[16];
  {
    u64 wb = packed[(size_t)(i0 + sr) * 48 + (jbase >> 6)];
    if (GAT) gat_w(sv, sdst, wb, jbase, jq, wv, zacc);
    else     gcn_w(dis, wb, i0 + sr, jbase, jq, wv);
  }
  for (int jb = 0; jb < JSL; jb += 64) {
    __syncthreads();
    t_store(Hs, hv, t);
#pragma unroll
    for (int q = 0; q < 16; q++) Ws[sr][jq + q] = f2bf(wv[q]);
    if (jb + 64 < JSL) {
      int j0 = jbase + jb + 64;
      hv = t_load(hin + (size_t)j0 * H, H, t);
      u64 wb = packed[(size_t)(i0 + sr) * 48 + (j0 >> 6)];
      if (GAT) gat_w(sv, sdst, wb, j0, jq, wv, zacc);
      else     gcn_w(dis, wb, i0 + sr, j0, jq, wv);
    }
    __syncthreads();
    mfma_tile(Ws, Hs, acc, wi, wf, il, kg);
  }
  if (GAT) {
    zacc += __shfl_xor(zacc, 1);
    zacc += __shfl_xor(zacc, 2);
    if ((t & 3) == 0) zpart[(size_t)blockIdx.y * N + i0 + sr] = zacc;
  }
  store_tile(outp + (size_t)blockIdx.y * NH, i0, wi, wf, il, kg, acc);
}

// ---------------------------------------------------------------------------
// Fused decoder + GEMM: computes xr tile = sigmoid(cs·Wdec+b) via decode-MFMA,
// writes xr (f32 out) and accumulates t1 partials = xr^T · Wg1 via main MFMA.
__global__ __launch_bounds__(256) void k_mmdec(const float* __restrict__ cs,
                                               const float* __restrict__ Wdec,
                                               const float* __restrict__ bdec,
                                               const float* __restrict__ Wg1,
                                               float* __restrict__ xr,
                                               float* __restrict__ outp) {
  __shared__ u16 As[64][72];   // xr^T tile [m-gene][k-cell]
  __shared__ u16 Bs[64][72];   // Wg1^T [n][k-cell]
  __shared__ u16 Wd[64][48];   // Wdec^T [m][q]
  __shared__ u16 Cs[64][48];   // cs [k][q]
  __shared__ float bs_s[64];
  int t = threadIdx.x;
  int g0 = blockIdx.x * 64;
  int c0 = blockIdx.y * JSL;
  int w = t >> 6, lane = t & 63, il = lane & 15, kg = lane >> 4;
  int wi = w >> 1, wf = w & 1;
  {  // stage Wdec^T + bias once per block
    int q = t >> 4, m4 = (t & 15) * 4;
#pragma unroll
    for (int it = 0; it < 2; it++) {
      int qq = q + it * 16;
      float4 v = *(const float4*)(Wdec + (size_t)qq * N + g0 + m4);
      Wd[m4 + 0][qq] = f2bf(v.x);
      Wd[m4 + 1][qq] = f2bf(v.y);
      Wd[m4 + 2][qq] = f2bf(v.z);
      Wd[m4 + 3][qq] = f2bf(v.w);
    }
    if (t < 64) bs_s[t] = bdec[g0 + t];
  }
  int kr = t >> 3, q4 = (t & 7) * 4;
  float4 cv0 = *(const float4*)(cs + (size_t)(c0 + kr) * CSD + q4);
  float4 cv1 = *(const float4*)(cs + (size_t)(c0 + 32 + kr) * CSD + q4);
  T4 bv = t_load(Wg1 + (size_t)c0 * H, H, t);
  f32x4 z = {0.f, 0.f, 0.f, 0.f};
  f32x4 acc[2][2] = {{z, z}, {z, z}};
  for (int cb = 0; cb < JSL; cb += 64) {
    __syncthreads();
    Cs[kr][q4 + 0] = f2bf(cv0.x); Cs[kr][q4 + 1] = f2bf(cv0.y);
    Cs[kr][q4 + 2] = f2bf(cv0.z); Cs[kr][q4 + 3] = f2bf(cv0.w);
    Cs[kr + 32][q4 + 0] = f2bf(cv1.x); Cs[kr + 32][q4 + 1] = f2bf(cv1.y);
    Cs[kr + 32][q4 + 2] = f2bf(cv1.z); Cs[kr + 32][q4 + 3] = f2bf(cv1.w);
    t_store(Bs, bv, t);
    if (cb + 64 < JSL) {
      cv0 = *(const float4*)(cs + (size_t)(c0 + cb + 64 + kr) * CSD + q4);
      cv1 = *(const float4*)(cs + (size_t)(c0 + cb + 96 + kr) * CSD + q4);
      bv = t_load(Wg1 + (size_t)(c0 + cb + 64) * H, H, t);
    }
    __syncthreads();
    // decode MFMA: D[m][k] = Wd[m][:] · Cs[k][:], K=32
    f32x4 dec[2][2] = {{z, z}, {z, z}};
    {
      s16x8 a0 = *(const s16x8*)&Wd[wi * 32 + il][kg * 8];
      s16x8 a1 = *(const s16x8*)&Wd[wi * 32 + 16 + il][kg * 8];
      s16x8 b0 = *(const s16x8*)&Cs[wf * 32 + il][kg * 8];
      s16x8 b1 = *(const s16x8*)&Cs[wf * 32 + 16 + il][kg * 8];
      dec[0][0] = __builtin_amdgcn_mfma_f32_16x16x32_bf16(a0, b0, dec[0][0], 0, 0, 0);
      dec[0][1] = __builtin_amdgcn_mfma_f32_16x16x32_bf16(a0, b1, dec[0][1], 0, 0, 0);
      dec[1][0] = __builtin_amdgcn_mfma_f32_16x16x32_bf16(a1, b0, dec[1][0], 0, 0, 0);
      dec[1][1] = __builtin_amdgcn_mfma_f32_16x16x32_bf16(a1, b1, dec[1][1], 0, 0, 0);
    }
    // bias + sigmoid; write As[m][k] bf16 + xr f32 (float4 per lane-quadrant)
#pragma unroll
    for (int ti = 0; ti < 2; ti++)
#pragma unroll
      for (int tf = 0; tf < 2; tf++) {
        int kcol = wf * 32 + tf * 16 + il;
        int mbase = wi * 32 + ti * 16 + kg * 4;
        float4 sv4;
        float* svp = (float*)&sv4;
#pragma unroll
        for (int r = 0; r < 4; r++) {
          float pre = dec[ti][tf][r] + bs_s[mbase + r];
          float sg = 1.f / (1.f + __expf(-pre));
          svp[r] = sg;
          As[mbase + r][kcol] = f2bf(sg);
        }
        *(float4*)(xr + (size_t)(c0 + cb + kcol) * N + g0 + mbase) = sv4;
      }
    __syncthreads();
    mfma_tile(As, Bs, acc, wi, wf, il, kg);
  }
  store_tile(outp + (size_t)blockIdx.y * NH, g0, wi, wf, il, kg, acc);
}

// ---------------------------------------------------------------------------
// Reduce nparts partial h buffers -> h f32, fused with s_dst/s_src dots.
__global__ __launch_bounds__(256) void k_reduce_sd(const float* __restrict__ src,
                                                   int nparts,
                                                   const float* __restrict__ a,
                                                   float* __restrict__ h,
                                                   float* __restrict__ sdst,
                                                   float* __restrict__ ssrc) {
  int row = blockIdx.x * 4 + (threadIdx.x >> 6);
  int lane = threadIdx.x & 63;
  size_t off = (size_t)row * H + lane;
  float v = 0.f;
  for (int p = 0; p < nparts; p++) v += src[(size_t)p * NH + off];
  h[off] = v;
  float d1 = v * a[lane];
  float d2 = v * a[H + lane];
  for (int o = 32; o; o >>= 1) {
    d1 += __shfl_xor(d1, o);
    d2 += __shfl_xor(d2, o);
  }
  if (lane == 0) { sdst[row] = d1; ssrc[row] = d2; }
}

// ---------------------------------------------------------------------------
// Generic 16-way float4 partial reduce: dst = sum_p src[p].
__global__ __launch_bounds__(256) void k_reduce(const float4* __restrict__ src,
                                                int nparts,
                                                float4* __restrict__ dst) {
  int idx = blockIdx.x * 256 + threadIdx.x;
  float4 v = {0, 0, 0, 0};
  for (int p = 0; p < nparts; p++) {
    float4 u = src[(size_t)p * (NH / 4) + idx];
    v.x += u.x; v.y += u.y; v.z += u.z; v.w += u.w;
  }
  dst[idx] = v;
}

// ---------------------------------------------------------------------------
// VAE + diffusion fusion; reduces hacc partials AND Z partials on load.
__global__ __launch_bounds__(256) void k_vae(const float* __restrict__ hacc,
                                             int nparts,
                                             const float* __restrict__ zpart,
                                             const float* __restrict__ eps,
                                             const float* __restrict__ Wmu,
                                             const float* __restrict__ bmu,
                                             const float* __restrict__ Wlv,
                                             const float* __restrict__ blv,
                                             const float* __restrict__ Wd,
                                             const float* __restrict__ bd,
                                             float* __restrict__ mu_o,
                                             float* __restrict__ lv_o,
                                             float* __restrict__ cs_o,
                                             float* __restrict__ ie) {
  __shared__ float hs[16][65];
  __shared__ float zs[16][17];
  __shared__ float wmu_s[64 * 16];
  __shared__ float wlv_s[64 * 16];
  __shared__ float wd_s[80 * 32];
  int t = threadIdx.x;
  int row0 = blockIdx.x * 16;
  {
    int rr = t >> 4, pp = t & 15;
    float zv = zpart[(size_t)pp * N + row0 + rr];
    zv += __shfl_xor(zv, 1);
    zv += __shfl_xor(zv, 2);
    zv += __shfl_xor(zv, 4);
    zv += __shfl_xor(zv, 8);
    float zi = 1.0f / fmaxf(zv, 1e-30f);
    const float4* g4 = (const float4*)(hacc + (size_t)row0 * H);
    float4 v = {0, 0, 0, 0};
    for (int p = 0; p < nparts; p++) {
      float4 u = g4[(size_t)p * (NH / 4) + t];
      v.x += u.x; v.y += u.y; v.z += u.z; v.w += u.w;
    }
    int c0 = (t & 15) * 4;
    float e0 = v.x * zi, e1 = v.y * zi, e2 = v.z * zi, e3 = v.w * zi;
    hs[rr][c0 + 0] = e0 > 0.f ? e0 : __expf(e0) - 1.f;
    hs[rr][c0 + 1] = e1 > 0.f ? e1 : __expf(e1) - 1.f;
    hs[rr][c0 + 2] = e2 > 0.f ? e2 : __expf(e2) - 1.f;
    hs[rr][c0 + 3] = e3 > 0.f ? e3 : __expf(e3) - 1.f;
  }
#pragma unroll
  for (int k = 0; k < 4; k++) {
    int lin = t + k * 256;
    wmu_s[lin] = Wmu[lin];
    wlv_s[lin] = Wlv[lin];
  }
#pragma unroll
  for (int k = 0; k < 10; k++) {
    int lin = t + k * 256;
    wd_s[lin] = Wd[lin];
  }
  __syncthreads();
  int r = t >> 4, kk = t & 15;
  float mu = bmu[kk], lv = blv[kk];
#pragma unroll 8
  for (int l = 0; l < 64; l++) {
    float hv = hs[r][l];
    mu += hv * wmu_s[l * 16 + kk];
    lv += hv * wlv_s[l * 16 + kk];
  }
  float zc = mu + eps[(size_t)(row0 + r) * CAUS + kk] * __expf(0.5f * lv);
  mu_o[(size_t)(row0 + r) * CAUS + kk] = mu;
  lv_o[(size_t)(row0 + r) * CAUS + kk] = lv;
  zs[r][kk] = zc;
  __syncthreads();
#pragma unroll
  for (int p = 0; p < 2; p++) {
    int lin = t + p * 256;
    int rr = lin >> 5, c = lin & 31;
    float acc = bd[c];
#pragma unroll 4
    for (int q = 0; q < 16; q++) acc += zs[rr][q] * wd_s[q * 32 + c];
#pragma unroll 8
    for (int l = 0; l < 64; l++) acc += hs[rr][l] * wd_s[(16 + l) * 32 + c];
    float v = fmaxf(acc, 0.f);
    cs_o[(size_t)(row0 + rr) * CSD + c] = v;
    ie[(size_t)(row0 + rr) * 96 + 64 + c] = v;
  }
}

// ---------------------------------------------------------------------------
// t2 = relu(sum_p h1part*dis) @ W2. 4 rows/block.
__global__ __launch_bounds__(256) void k_h1w2(const float* __restrict__ h1src,
                                              int nparts,
                                              const float* __restrict__ dis,
                                              const float* __restrict__ W2,
                                              float* __restrict__ t2) {
  __shared__ float w2s[64 * 64];
  __shared__ float hs[4][65];
  int t = threadIdx.x;
  int row0 = blockIdx.x * 4;
#pragma unroll
  for (int k = 0; k < 16; k++) w2s[t + k * 256] = W2[t + k * 256];
  {
    int rr = t >> 6;
    size_t off = (size_t)row0 * H + t;
    float v = 0.f;
    for (int p = 0; p < nparts; p++) v += h1src[(size_t)p * NH + off];
    hs[rr][t & 63] = fmaxf(v * dis[row0 + rr], 0.f);
  }
  __syncthreads();
  int r = t >> 6, f = t & 63;
  float acc = 0.f;
#pragma unroll 8
  for (int l = 0; l < 64; l++) acc += hs[r][l] * w2s[l * 64 + f];
  t2[(size_t)(row0 + r) * H + f] = acc;
}

// ---------------------------------------------------------------------------
// h2 = relu(sum_p h2part * dis); also writes ie[:, :64].
__global__ __launch_bounds__(256) void k_fin2(const float* __restrict__ h2src,
                                              int nparts,
                                              const float* __restrict__ dis,
                                              float* __restrict__ h2,
                                              float* __restrict__ ie) {
  int idx = blockIdx.x * 256 + threadIdx.x;
  int row = idx >> 6, f = idx & 63;
  float v = 0.f;
  for (int p = 0; p < nparts; p++) v += h2src[(size_t)p * NH + idx];
  v = fmaxf(v * dis[row], 0.f);
  h2[idx] = v;
  ie[(size_t)row * 96 + f] = v;
}

// ---------------------------------------------------------------------------
extern "C" void kernel_launch(void* const* d_in, const int* in_sizes, int n_in,
                              void* d_out, int out_size, void* d_ws, size_t ws_size,
                              hipStream_t stream) {
  const float* x    = (const float*)d_in[0];
  const int*   adj  = (const int*)d_in[1];
  const float* eps  = (const float*)d_in[2];
  const float* Wgat = (const float*)d_in[3];
  const float* agat = (const float*)d_in[4];
  const float* Wmu  = (const float*)d_in[5];
  const float* bmu  = (const float*)d_in[6];
  const float* Wlv  = (const float*)d_in[7];
  const float* blv  = (const float*)d_in[8];
  const float* Wdif = (const float*)d_in[9];
  const float* bdif = (const float*)d_in[10];
  const float* Wdec = (const float*)d_in[11];
  const float* bdec = (const float*)d_in[12];
  const float* Wg1  = (const float*)d_in[13];
  const float* Wg2  = (const float*)d_in[14];

  float* out = (float*)d_out;
  float* xr  = out;                       // (3072,3072)
  float* h2  = out + 9437184;             // (3072,64)
  float* ie  = out + 9633792;             // (3072,96)
  float* cs  = out + 9928704;             // (3072,32)
  float* muo = out + 10027008;            // (3072,16)
  float* lvo = out + 10076160;            // (3072,16)

  // Workspace (~17 MB of 256 MB)
  u64* packed = (u64*)d_ws;               // 3072*48 u64 = 1.18 MB
  float* wf    = (float*)d_ws + 294912;
  float* part  = wf;                      // SLICES*NH f32 partials (reused 4x)
  float* h     = part + (size_t)SLICES * NH;
  float* t1    = h + NH;
  float* t2    = t1 + NH;
  float* sdst  = t2 + NH;
  float* ssrc  = sdst + N;
  float* dis   = ssrc + N;
  float* zpart = dis + N;                 // SLICES*N

  // ---- adjacency pack + degrees
  k_pack<<<768, 256, 0, stream>>>(adj, packed, dis);
  // ---- GAT: h = x^T @ W_gat
  k_mm<<<dim3(48, SLICES), 256, 0, stream>>>(x, N, Wgat, H, part);
  k_reduce_sd<<<768, 256, 0, stream>>>(part, SLICES, agat, h, sdst, ssrc);
  k_agg<1><<<dim3(48, SLICES), 256, 0, stream>>>(h, packed, sdst, ssrc, dis, part, zpart);
  // ---- VAE + diffusion fusion (reduces hacc + Z partials on load)
  k_vae<<<192, 256, 0, stream>>>(part, SLICES, zpart, eps, Wmu, bmu, Wlv, blv,
                                 Wdif, bdif, muo, lvo, cs, ie);
  // ---- fused decoder + GCN GEMM (writes xr output + t1 partials)
  k_mmdec<<<dim3(48, SLICES), 256, 0, stream>>>(cs, Wdec, bdec, Wg1, xr, part);
  k_reduce<<<192, 256, 0, stream>>>((const float4*)part, SLICES, (float4*)t1);
  k_agg<0><<<dim3(48, SLICES), 256, 0, stream>>>(t1, packed, sdst, ssrc, dis, part, nullptr);
  k_h1w2<<<768, 256, 0, stream>>>(part, SLICES, dis, Wg2, t2);
  k_agg<0><<<dim3(48, SLICES), 256, 0, stream>>>(t2, packed, sdst, ssrc, dis, part, nullptr);
  k_fin2<<<768, 256, 0, stream>>>(part, SLICES, dis, h2, ie);
}